// Round 2
// baseline (3741.660 us; speedup 1.0000x reference)
//
#include <hip/hip_runtime.h>

#define NN 50000
#define NE 800000
#define NG 64
#define FD 128

// ---------- CSR build ----------

__global__ void k_count(const int* __restrict__ dst, int* __restrict__ indeg) {
  int e = blockIdx.x * 256 + threadIdx.x;
  if (e < NE) atomicAdd(&indeg[dst[e]], 1);
}

__global__ void k_scan(const int* __restrict__ indeg, int* __restrict__ row_off) {
  __shared__ int sums[256];
  int t = threadIdx.x;
  const int CHUNK = (NN + 255) / 256;  // 196
  int base = t * CHUNK;
  int s = 0;
  for (int i = 0; i < CHUNK; ++i) {
    int idx = base + i;
    if (idx < NN) s += indeg[idx];
  }
  sums[t] = s;
  __syncthreads();
  // Hillis-Steele inclusive scan over 256 partials
  for (int off = 1; off < 256; off <<= 1) {
    int v = (t >= off) ? sums[t - off] : 0;
    __syncthreads();
    sums[t] += v;
    __syncthreads();
  }
  int run = (t == 0) ? 0 : sums[t - 1];  // exclusive prefix
  for (int i = 0; i < CHUNK; ++i) {
    int idx = base + i;
    if (idx < NN) { row_off[idx] = run; run += indeg[idx]; }
  }
  if (t == 255) row_off[NN] = sums[255];
}

__global__ void k_dinv_cursor(const int* __restrict__ indeg, const int* __restrict__ row_off,
                              float* __restrict__ dinv, int* __restrict__ cursor) {
  int i = blockIdx.x * 256 + threadIdx.x;
  if (i < NN) {
    dinv[i] = rsqrtf((float)(indeg[i] + 1));  // +1 self-loop
    cursor[i] = row_off[i];
  }
}

__global__ void k_fill(const int* __restrict__ src, const int* __restrict__ dst,
                       int* __restrict__ cursor, int* __restrict__ csr_src) {
  int e = blockIdx.x * 256 + threadIdx.x;
  if (e < NE) {
    int pos = atomicAdd(&cursor[dst[e]], 1);
    csr_src[pos] = src[e];
  }
}

// ---------- dense: g[i][:] = dinv[i] * (h[i][:] @ W) ----------
// 64 rows x 128 cols per 256-thread block; LDS-staged h (k-chunked) and W.
// Each thread: 4 rows x 8 cols.

__global__ __launch_bounds__(256) void k_matmul(const float* __restrict__ h,
                                                const float* __restrict__ W,
                                                const float* __restrict__ dinv,
                                                float* __restrict__ g) {
  __shared__ float h_s[64][36];   // stride 36 floats = 144B (16B-aligned rows, banks spread)
  __shared__ float w_s[32][128];
  int tid = threadIdx.x;
  int cg = tid & 15;   // cols cg*8 .. +7
  int rg = tid >> 4;   // rows rg*4 .. +3
  int row0 = blockIdx.x * 64;
  float acc[4][8] = {};

  for (int kc = 0; kc < 4; ++kc) {
    // stage h[row0..+64][kc*32..+32] : 512 float4s, 2 per thread, coalesced
#pragma unroll
    for (int i = 0; i < 2; ++i) {
      int idx = tid + 256 * i;       // 0..511
      int r = idx >> 3;              // 0..63
      int o = (idx & 7) * 4;         // 0..28
      int grow = row0 + r;
      if (grow > NN - 1) grow = NN - 1;
      float4 v = *(const float4*)(h + (size_t)grow * FD + kc * 32 + o);
      h_s[r][o + 0] = v.x; h_s[r][o + 1] = v.y;
      h_s[r][o + 2] = v.z; h_s[r][o + 3] = v.w;
    }
    // stage W[kc*32..+32][:] : 1024 float4s, 4 per thread, fully coalesced
#pragma unroll
    for (int i = 0; i < 4; ++i) {
      int p = tid + 256 * i;         // 0..1023
      int k = p >> 5;
      int j4 = p & 31;
      float4 v = *(const float4*)(W + (size_t)(kc * 32 + k) * FD + j4 * 4);
      *(float4*)&w_s[k][j4 * 4] = v;
    }
    __syncthreads();

#pragma unroll
    for (int k4 = 0; k4 < 8; ++k4) {
      float4 hv[4];
#pragma unroll
      for (int rr = 0; rr < 4; ++rr)
        hv[rr] = *(const float4*)&h_s[rg * 4 + rr][k4 * 4];
#pragma unroll
      for (int kk = 0; kk < 4; ++kk) {
        float4 w0 = *(const float4*)&w_s[k4 * 4 + kk][cg * 8];
        float4 w1 = *(const float4*)&w_s[k4 * 4 + kk][cg * 8 + 4];
#pragma unroll
        for (int rr = 0; rr < 4; ++rr) {
          float hh = (kk == 0) ? hv[rr].x : (kk == 1) ? hv[rr].y : (kk == 2) ? hv[rr].z : hv[rr].w;
          acc[rr][0] = fmaf(hh, w0.x, acc[rr][0]);
          acc[rr][1] = fmaf(hh, w0.y, acc[rr][1]);
          acc[rr][2] = fmaf(hh, w0.z, acc[rr][2]);
          acc[rr][3] = fmaf(hh, w0.w, acc[rr][3]);
          acc[rr][4] = fmaf(hh, w1.x, acc[rr][4]);
          acc[rr][5] = fmaf(hh, w1.y, acc[rr][5]);
          acc[rr][6] = fmaf(hh, w1.z, acc[rr][6]);
          acc[rr][7] = fmaf(hh, w1.w, acc[rr][7]);
        }
      }
    }
    __syncthreads();
  }

#pragma unroll
  for (int rr = 0; rr < 4; ++rr) {
    int r = row0 + rg * 4 + rr;
    if (r < NN) {
      float d = dinv[r];
      float4 o1, o2;
      o1.x = acc[rr][0] * d; o1.y = acc[rr][1] * d; o1.z = acc[rr][2] * d; o1.w = acc[rr][3] * d;
      o2.x = acc[rr][4] * d; o2.y = acc[rr][5] * d; o2.z = acc[rr][6] * d; o2.w = acc[rr][7] * d;
      *(float4*)(g + (size_t)r * FD + cg * 8) = o1;
      *(float4*)(g + (size_t)r * FD + cg * 8 + 4) = o2;
    }
  }
}

// ---------- sparse: out[i] = relu(dinv[i]*(sum_{s in N(i)} g[s] + g[i]) + b) ----------
// 32 lanes per node (float4 per lane), 8 nodes per 256-thread block.
// Edge loop unrolled x4: 4 independent 512B gathers in flight.

__global__ __launch_bounds__(256) void k_agg(const float* __restrict__ g,
                                             const int* __restrict__ row_off,
                                             const int* __restrict__ csr_src,
                                             const float* __restrict__ dinv,
                                             const float* __restrict__ bias,
                                             float* __restrict__ out) {
  int node = blockIdx.x * 8 + (threadIdx.x >> 5);
  int f4 = threadIdx.x & 31;
  if (node >= NN) return;
  const float4* gp = (const float4*)g;
  float4 self = gp[(size_t)node * 32 + f4];
  float a0 = self.x, a1 = self.y, a2 = self.z, a3 = self.w;
  float b0 = 0.f, b1 = 0.f, b2 = 0.f, b3 = 0.f;
  int e0 = row_off[node], e1 = row_off[node + 1];
  int e = e0;
  for (; e + 4 <= e1; e += 4) {
    int s0 = csr_src[e + 0];
    int s1 = csr_src[e + 1];
    int s2 = csr_src[e + 2];
    int s3 = csr_src[e + 3];
    float4 v0 = gp[(size_t)s0 * 32 + f4];
    float4 v1 = gp[(size_t)s1 * 32 + f4];
    float4 v2 = gp[(size_t)s2 * 32 + f4];
    float4 v3 = gp[(size_t)s3 * 32 + f4];
    a0 += v0.x + v1.x; a1 += v0.y + v1.y; a2 += v0.z + v1.z; a3 += v0.w + v1.w;
    b0 += v2.x + v3.x; b1 += v2.y + v3.y; b2 += v2.z + v3.z; b3 += v2.w + v3.w;
  }
  for (; e < e1; ++e) {
    int s = csr_src[e];
    float4 v = gp[(size_t)s * 32 + f4];
    a0 += v.x; a1 += v.y; a2 += v.z; a3 += v.w;
  }
  float d = dinv[node];
  float4 bv = ((const float4*)bias)[f4];
  float4 o;
  o.x = fmaxf(d * (a0 + b0) + bv.x, 0.f);
  o.y = fmaxf(d * (a1 + b1) + bv.y, 0.f);
  o.z = fmaxf(d * (a2 + b2) + bv.z, 0.f);
  o.w = fmaxf(d * (a3 + b3) + bv.w, 0.f);
  *(float4*)(out + (size_t)node * FD + f4 * 4) = o;
}

// ---------- pooling: batch sorted -> run-length local accumulate ----------

__global__ void k_pool(const float* __restrict__ h, const int* __restrict__ batch,
                       float* __restrict__ addp, float* __restrict__ cnt,
                       unsigned int* __restrict__ maxp) {
  const int PN = 64;
  int f = threadIdx.x;  // 0..127
  int n0 = blockIdx.x * PN;
  if (n0 >= NN) return;
  int n1 = n0 + PN; if (n1 > NN) n1 = NN;
  int curg = batch[n0];
  float s = 0.f, m = 0.f;
  int c = 0;
  for (int n = n0; n < n1; ++n) {
    int gi = batch[n];
    if (gi != curg) {
      atomicAdd(&addp[curg * FD + f], s);
      atomicMax(&maxp[curg * FD + f], __float_as_uint(m));
      if (f == 0) atomicAdd(&cnt[curg], (float)c);
      s = 0.f; m = 0.f; c = 0; curg = gi;
    }
    float v = h[(size_t)n * FD + f];
    s += v;
    m = fmaxf(m, v);
    c += 1;
  }
  atomicAdd(&addp[curg * FD + f], s);
  atomicMax(&maxp[curg * FD + f], __float_as_uint(m));  // h >= 0 post-relu
  if (f == 0) atomicAdd(&cnt[curg], (float)c);
}

// ---------- enc assembly + 2-layer MLP ----------

__global__ void k_final(const float* __restrict__ addp, const float* __restrict__ cnt,
                        const unsigned int* __restrict__ maxp,
                        const float* __restrict__ l1w, const float* __restrict__ l1b,
                        const float* __restrict__ l2w, const float* __restrict__ l2b,
                        float* __restrict__ d_out) {
  __shared__ float enc_s[384];
  __shared__ float hid_s[128];
  int gph = blockIdx.x, j = threadIdx.x;
  float a = addp[gph * FD + j];
  float c = cnt[gph];
  float mn = a / fmaxf(c, 1.f);
  float mx = __uint_as_float(maxp[gph * FD + j]);
  enc_s[j] = a; enc_s[128 + j] = mn; enc_s[256 + j] = mx;
  float* enc_out = d_out + 2 * NG;
  enc_out[gph * 384 + j] = a;
  enc_out[gph * 384 + 128 + j] = mn;
  enc_out[gph * 384 + 256 + j] = mx;
  __syncthreads();
  float sacc = l1b[j];
  for (int k = 0; k < 384; ++k) sacc = fmaf(enc_s[k], l1w[k * FD + j], sacc);
  hid_s[j] = fmaxf(sacc, 0.f);
  __syncthreads();
  if (j < 2) {
    float o = l2b[j];
    for (int k = 0; k < FD; ++k) o = fmaf(hid_s[k], l2w[k * 2 + j], o);
    d_out[gph * 2 + j] = o;
  }
}

extern "C" void kernel_launch(void* const* d_in, const int* in_sizes, int n_in,
                              void* d_out, int out_size, void* d_ws, size_t ws_size,
                              hipStream_t stream) {
  const float* x      = (const float*)d_in[0];
  const int*   edge   = (const int*)d_in[1];
  const int*   batch  = (const int*)d_in[2];
  const float* conv_w = (const float*)d_in[3];
  const float* conv_b = (const float*)d_in[4];
  const float* l1w    = (const float*)d_in[5];
  const float* l1b    = (const float*)d_in[6];
  const float* l2w    = (const float*)d_in[7];
  const float* l2b    = (const float*)d_in[8];
  float* out = (float*)d_out;

  const int* esrc = edge;        // edge_index[0]
  const int* edst = edge + NE;   // edge_index[1]

  char* wsp = (char*)d_ws;
  auto alloc = [&](size_t bytes) -> char* {
    char* p = wsp;
    wsp += (bytes + 255) & ~(size_t)255;
    return p;
  };
  float* bufA    = (float*)alloc(sizeof(float) * NN * FD);
  float* bufB    = (float*)alloc(sizeof(float) * NN * FD);
  int*   csr_src = (int*)alloc(sizeof(int) * NE);
  int*   indeg   = (int*)alloc(sizeof(int) * NN);
  int*   row_off = (int*)alloc(sizeof(int) * (NN + 1));
  int*   cursor  = (int*)alloc(sizeof(int) * NN);
  float* dinv    = (float*)alloc(sizeof(float) * NN);
  float* addp    = (float*)alloc(sizeof(float) * NG * FD);
  float* cnt     = (float*)alloc(sizeof(float) * NG);
  unsigned int* maxp = (unsigned int*)alloc(sizeof(unsigned int) * NG * FD);

  hipMemsetAsync(indeg, 0, sizeof(int) * NN, stream);
  hipMemsetAsync(addp, 0, sizeof(float) * NG * FD, stream);
  hipMemsetAsync(cnt, 0, sizeof(float) * NG, stream);
  hipMemsetAsync(maxp, 0, sizeof(unsigned int) * NG * FD, stream);

  k_count<<<(NE + 255) / 256, 256, 0, stream>>>(edst, indeg);
  k_scan<<<1, 256, 0, stream>>>(indeg, row_off);
  k_dinv_cursor<<<(NN + 255) / 256, 256, 0, stream>>>(indeg, row_off, dinv, cursor);
  k_fill<<<(NE + 255) / 256, 256, 0, stream>>>(esrc, edst, cursor, csr_src);

  const float* hin = x;
  for (int l = 0; l < 3; ++l) {
    k_matmul<<<(NN + 63) / 64, 256, 0, stream>>>(hin, conv_w + l * FD * FD, dinv, bufA);
    k_agg<<<(NN + 7) / 8, 256, 0, stream>>>(bufA, row_off, csr_src, dinv, conv_b + l * FD, bufB);
    hin = bufB;
  }

  k_pool<<<(NN + 63) / 64, 128, 0, stream>>>(bufB, batch, addp, cnt, maxp);
  k_final<<<NG, 128, 0, stream>>>(addp, cnt, maxp, l1w, l1b, l2w, l2b, out);
}

// Round 3
// 502.071 us; speedup vs baseline: 7.4524x; 7.4524x over previous
//
#include <hip/hip_runtime.h>

#define NN 50000
#define NE 800000
#define NG 64
#define FD 128

// ---------- CSR build ----------

__global__ void k_count(const int* __restrict__ dst, int* __restrict__ indeg) {
  int e = blockIdx.x * 256 + threadIdx.x;
  if (e < NE) atomicAdd(&indeg[dst[e]], 1);
}

__global__ void k_scan(const int* __restrict__ indeg, int* __restrict__ row_off) {
  __shared__ int sums[256];
  int t = threadIdx.x;
  const int CHUNK = (NN + 255) / 256;  // 196
  int base = t * CHUNK;
  int s = 0;
  for (int i = 0; i < CHUNK; ++i) {
    int idx = base + i;
    if (idx < NN) s += indeg[idx];
  }
  sums[t] = s;
  __syncthreads();
  for (int off = 1; off < 256; off <<= 1) {
    int v = (t >= off) ? sums[t - off] : 0;
    __syncthreads();
    sums[t] += v;
    __syncthreads();
  }
  int run = (t == 0) ? 0 : sums[t - 1];
  for (int i = 0; i < CHUNK; ++i) {
    int idx = base + i;
    if (idx < NN) { row_off[idx] = run; run += indeg[idx]; }
  }
  if (t == 255) row_off[NN] = sums[255];
}

__global__ void k_dinv_cursor(const int* __restrict__ indeg, const int* __restrict__ row_off,
                              float* __restrict__ dinv, int* __restrict__ cursor) {
  int i = blockIdx.x * 256 + threadIdx.x;
  if (i < NN) {
    dinv[i] = rsqrtf((float)(indeg[i] + 1));
    cursor[i] = row_off[i];
  }
}

__global__ void k_fill(const int* __restrict__ src, const int* __restrict__ dst,
                       int* __restrict__ cursor, int* __restrict__ csr_src) {
  int e = blockIdx.x * 256 + threadIdx.x;
  if (e < NE) {
    int pos = atomicAdd(&cursor[dst[e]], 1);
    csr_src[pos] = src[e];
  }
}

// ---------- dense: g[i][:] = dinv[i] * (h[i][:] @ W) ----------
// 64 rows x 128 cols per 256-thread block. LDS: h chunk [64][33] (padded),
// W chunk [32][128]. Thread tile 4 rows x 8 cols, scalar h_s reads
// (wave-broadcast), float4 w_s reads. k-loop unroll kept at 4 to keep
// live ranges short (R2's full unroll spilled to scratch: VGPR=256,
// 1.35 GB scratch fetch per dispatch).

__global__ __launch_bounds__(256) void k_matmul(const float* __restrict__ h,
                                                const float* __restrict__ W,
                                                const float* __restrict__ dinv,
                                                float* __restrict__ g) {
  __shared__ float h_s[64][33];
  __shared__ float w_s[32][128];
  int tid = threadIdx.x;
  int cg = tid & 15;   // 16 col-groups * 8 cols
  int rg = tid >> 4;   // 16 row-groups * 4 rows
  int row0 = blockIdx.x * 64;
  float acc[4][8] = {};

  for (int kc = 0; kc < 4; ++kc) {
    // stage h[row0..+64][kc*32..+32]: 512 float4 loads, 2 per thread
#pragma unroll
    for (int i = 0; i < 2; ++i) {
      int idx = tid + 256 * i;  // 0..511
      int r = idx >> 3;
      int o = (idx & 7) * 4;
      int grow = row0 + r;
      if (grow > NN - 1) grow = NN - 1;
      float4 v = *(const float4*)(h + (size_t)grow * FD + kc * 32 + o);
      h_s[r][o + 0] = v.x; h_s[r][o + 1] = v.y;
      h_s[r][o + 2] = v.z; h_s[r][o + 3] = v.w;
    }
    // stage W[kc*32..+32][:]: 1024 float4 loads, 4 per thread
#pragma unroll
    for (int i = 0; i < 4; ++i) {
      int p = tid + 256 * i;  // 0..1023
      int k = p >> 5;
      int j4 = (p & 31) * 4;
      *(float4*)&w_s[k][j4] = *(const float4*)(W + (size_t)(kc * 32 + k) * FD + j4);
    }
    __syncthreads();

#pragma unroll 4
    for (int k = 0; k < 32; ++k) {
      float4 w0 = *(const float4*)&w_s[k][cg * 8];
      float4 w1 = *(const float4*)&w_s[k][cg * 8 + 4];
#pragma unroll
      for (int rr = 0; rr < 4; ++rr) {
        float hh = h_s[rg * 4 + rr][k];
        acc[rr][0] = fmaf(hh, w0.x, acc[rr][0]);
        acc[rr][1] = fmaf(hh, w0.y, acc[rr][1]);
        acc[rr][2] = fmaf(hh, w0.z, acc[rr][2]);
        acc[rr][3] = fmaf(hh, w0.w, acc[rr][3]);
        acc[rr][4] = fmaf(hh, w1.x, acc[rr][4]);
        acc[rr][5] = fmaf(hh, w1.y, acc[rr][5]);
        acc[rr][6] = fmaf(hh, w1.z, acc[rr][6]);
        acc[rr][7] = fmaf(hh, w1.w, acc[rr][7]);
      }
    }
    __syncthreads();
  }

#pragma unroll
  for (int rr = 0; rr < 4; ++rr) {
    int r = row0 + rg * 4 + rr;
    if (r < NN) {
      float d = dinv[r];
      float4 o1, o2;
      o1.x = acc[rr][0] * d; o1.y = acc[rr][1] * d; o1.z = acc[rr][2] * d; o1.w = acc[rr][3] * d;
      o2.x = acc[rr][4] * d; o2.y = acc[rr][5] * d; o2.z = acc[rr][6] * d; o2.w = acc[rr][7] * d;
      *(float4*)(g + (size_t)r * FD + cg * 8) = o1;
      *(float4*)(g + (size_t)r * FD + cg * 8 + 4) = o2;
    }
  }
}

// ---------- sparse: out[i] = relu(dinv[i]*(sum_{s in N(i)} g[s] + g[i]) + b) ----------
// 32 lanes per node (float4 per lane), 8 nodes per 256-thread block.
// Edge loop unrolled x4: 4 independent 512B gathers in flight.

__global__ __launch_bounds__(256) void k_agg(const float* __restrict__ g,
                                             const int* __restrict__ row_off,
                                             const int* __restrict__ csr_src,
                                             const float* __restrict__ dinv,
                                             const float* __restrict__ bias,
                                             float* __restrict__ out) {
  int node = blockIdx.x * 8 + (threadIdx.x >> 5);
  int f4 = threadIdx.x & 31;
  if (node >= NN) return;
  const float4* gp = (const float4*)g;
  float4 self = gp[(size_t)node * 32 + f4];
  float a0 = self.x, a1 = self.y, a2 = self.z, a3 = self.w;
  float b0 = 0.f, b1 = 0.f, b2 = 0.f, b3 = 0.f;
  int e0 = row_off[node], e1 = row_off[node + 1];
  int e = e0;
  for (; e + 4 <= e1; e += 4) {
    int s0 = csr_src[e + 0];
    int s1 = csr_src[e + 1];
    int s2 = csr_src[e + 2];
    int s3 = csr_src[e + 3];
    float4 v0 = gp[(size_t)s0 * 32 + f4];
    float4 v1 = gp[(size_t)s1 * 32 + f4];
    float4 v2 = gp[(size_t)s2 * 32 + f4];
    float4 v3 = gp[(size_t)s3 * 32 + f4];
    a0 += v0.x + v1.x; a1 += v0.y + v1.y; a2 += v0.z + v1.z; a3 += v0.w + v1.w;
    b0 += v2.x + v3.x; b1 += v2.y + v3.y; b2 += v2.z + v3.z; b3 += v2.w + v3.w;
  }
  for (; e < e1; ++e) {
    int s = csr_src[e];
    float4 v = gp[(size_t)s * 32 + f4];
    a0 += v.x; a1 += v.y; a2 += v.z; a3 += v.w;
  }
  float d = dinv[node];
  float4 bv = ((const float4*)bias)[f4];
  float4 o;
  o.x = fmaxf(d * (a0 + b0) + bv.x, 0.f);
  o.y = fmaxf(d * (a1 + b1) + bv.y, 0.f);
  o.z = fmaxf(d * (a2 + b2) + bv.z, 0.f);
  o.w = fmaxf(d * (a3 + b3) + bv.w, 0.f);
  *(float4*)(out + (size_t)node * FD + f4 * 4) = o;
}

// ---------- pooling ----------

__global__ void k_pool(const float* __restrict__ h, const int* __restrict__ batch,
                       float* __restrict__ addp, float* __restrict__ cnt,
                       unsigned int* __restrict__ maxp) {
  const int PN = 64;
  int f = threadIdx.x;  // 0..127
  int n0 = blockIdx.x * PN;
  if (n0 >= NN) return;
  int n1 = n0 + PN; if (n1 > NN) n1 = NN;
  int curg = batch[n0];
  float s = 0.f, m = 0.f;
  int c = 0;
  for (int n = n0; n < n1; ++n) {
    int gi = batch[n];
    if (gi != curg) {
      atomicAdd(&addp[curg * FD + f], s);
      atomicMax(&maxp[curg * FD + f], __float_as_uint(m));
      if (f == 0) atomicAdd(&cnt[curg], (float)c);
      s = 0.f; m = 0.f; c = 0; curg = gi;
    }
    float v = h[(size_t)n * FD + f];
    s += v;
    m = fmaxf(m, v);
    c += 1;
  }
  atomicAdd(&addp[curg * FD + f], s);
  atomicMax(&maxp[curg * FD + f], __float_as_uint(m));  // h >= 0 post-relu
  if (f == 0) atomicAdd(&cnt[curg], (float)c);
}

// ---------- enc assembly + 2-layer MLP ----------

__global__ void k_final(const float* __restrict__ addp, const float* __restrict__ cnt,
                        const unsigned int* __restrict__ maxp,
                        const float* __restrict__ l1w, const float* __restrict__ l1b,
                        const float* __restrict__ l2w, const float* __restrict__ l2b,
                        float* __restrict__ d_out) {
  __shared__ float enc_s[384];
  __shared__ float hid_s[128];
  int gph = blockIdx.x, j = threadIdx.x;
  float a = addp[gph * FD + j];
  float c = cnt[gph];
  float mn = a / fmaxf(c, 1.f);
  float mx = __uint_as_float(maxp[gph * FD + j]);
  enc_s[j] = a; enc_s[128 + j] = mn; enc_s[256 + j] = mx;
  float* enc_out = d_out + 2 * NG;
  enc_out[gph * 384 + j] = a;
  enc_out[gph * 384 + 128 + j] = mn;
  enc_out[gph * 384 + 256 + j] = mx;
  __syncthreads();
  float sacc = l1b[j];
  for (int k = 0; k < 384; ++k) sacc = fmaf(enc_s[k], l1w[k * FD + j], sacc);
  hid_s[j] = fmaxf(sacc, 0.f);
  __syncthreads();
  if (j < 2) {
    float o = l2b[j];
    for (int k = 0; k < FD; ++k) o = fmaf(hid_s[k], l2w[k * 2 + j], o);
    d_out[gph * 2 + j] = o;
  }
}

extern "C" void kernel_launch(void* const* d_in, const int* in_sizes, int n_in,
                              void* d_out, int out_size, void* d_ws, size_t ws_size,
                              hipStream_t stream) {
  const float* x      = (const float*)d_in[0];
  const int*   edge   = (const int*)d_in[1];
  const int*   batch  = (const int*)d_in[2];
  const float* conv_w = (const float*)d_in[3];
  const float* conv_b = (const float*)d_in[4];
  const float* l1w    = (const float*)d_in[5];
  const float* l1b    = (const float*)d_in[6];
  const float* l2w    = (const float*)d_in[7];
  const float* l2b    = (const float*)d_in[8];
  float* out = (float*)d_out;

  const int* esrc = edge;
  const int* edst = edge + NE;

  char* wsp = (char*)d_ws;
  auto alloc = [&](size_t bytes) -> char* {
    char* p = wsp;
    wsp += (bytes + 255) & ~(size_t)255;
    return p;
  };
  float* bufA    = (float*)alloc(sizeof(float) * NN * FD);
  float* bufB    = (float*)alloc(sizeof(float) * NN * FD);
  int*   csr_src = (int*)alloc(sizeof(int) * NE);
  int*   indeg   = (int*)alloc(sizeof(int) * NN);
  int*   row_off = (int*)alloc(sizeof(int) * (NN + 1));
  int*   cursor  = (int*)alloc(sizeof(int) * NN);
  float* dinv    = (float*)alloc(sizeof(float) * NN);
  float* addp    = (float*)alloc(sizeof(float) * NG * FD);
  float* cnt     = (float*)alloc(sizeof(float) * NG);
  unsigned int* maxp = (unsigned int*)alloc(sizeof(unsigned int) * NG * FD);

  hipMemsetAsync(indeg, 0, sizeof(int) * NN, stream);
  hipMemsetAsync(addp, 0, sizeof(float) * NG * FD, stream);
  hipMemsetAsync(cnt, 0, sizeof(float) * NG, stream);
  hipMemsetAsync(maxp, 0, sizeof(unsigned int) * NG * FD, stream);

  k_count<<<(NE + 255) / 256, 256, 0, stream>>>(edst, indeg);
  k_scan<<<1, 256, 0, stream>>>(indeg, row_off);
  k_dinv_cursor<<<(NN + 255) / 256, 256, 0, stream>>>(indeg, row_off, dinv, cursor);
  k_fill<<<(NE + 255) / 256, 256, 0, stream>>>(esrc, edst, cursor, csr_src);

  const float* hin = x;
  for (int l = 0; l < 3; ++l) {
    k_matmul<<<(NN + 63) / 64, 256, 0, stream>>>(hin, conv_w + l * FD * FD, dinv, bufA);
    k_agg<<<(NN + 7) / 8, 256, 0, stream>>>(bufA, row_off, csr_src, dinv, conv_b + l * FD, bufB);
    hin = bufB;
  }

  k_pool<<<(NN + 63) / 64, 128, 0, stream>>>(bufB, batch, addp, cnt, maxp);
  k_final<<<NG, 128, 0, stream>>>(addp, cnt, maxp, l1w, l1b, l2w, l2b, out);
}

// Round 4
// 409.285 us; speedup vs baseline: 9.1419x; 1.2267x over previous
//
#include <hip/hip_runtime.h>

#define NN 50000
#define NE 800000
#define NG 64
#define FD 128
#define SCAN_NB ((NN + 255) / 256)   // 196 scan blocks

// ---------- CSR build ----------

__global__ void k_count(const int* __restrict__ dst, int* __restrict__ indeg) {
  int e = blockIdx.x * 256 + threadIdx.x;
  if (e < NE) atomicAdd(&indeg[dst[e]], 1);
}

// Hierarchical scan, stage 1: per-block local exclusive scan (coalesced) + block sums.
__global__ void k_scan1(const int* __restrict__ indeg, int* __restrict__ locpre,
                        int* __restrict__ blocksum) {
  __shared__ int sums[256];
  int t = threadIdx.x;
  int idx = blockIdx.x * 256 + t;
  int v = (idx < NN) ? indeg[idx] : 0;
  sums[t] = v;
  __syncthreads();
  for (int off = 1; off < 256; off <<= 1) {
    int u = (t >= off) ? sums[t - off] : 0;
    __syncthreads();
    sums[t] += u;
    __syncthreads();
  }
  if (idx < NN) locpre[idx] = sums[t] - v;  // exclusive
  if (t == 255) blocksum[blockIdx.x] = sums[255];
}

// Stage 2: scan the 196 block sums (single tiny block).
__global__ void k_scan2(int* __restrict__ blocksum, int* __restrict__ blockoff,
                        int* __restrict__ row_off) {
  __shared__ int sums[256];
  int t = threadIdx.x;
  int v = (t < SCAN_NB) ? blocksum[t] : 0;
  sums[t] = v;
  __syncthreads();
  for (int off = 1; off < 256; off <<= 1) {
    int u = (t >= off) ? sums[t - off] : 0;
    __syncthreads();
    sums[t] += u;
    __syncthreads();
  }
  if (t < SCAN_NB) blockoff[t] = sums[t] - v;  // exclusive
  if (t == 255) row_off[NN] = sums[255];       // total = NE
}

// Stage 3: final row offsets; also fused dinv + cursor init.
__global__ void k_scan3(const int* __restrict__ indeg, const int* __restrict__ locpre,
                        const int* __restrict__ blockoff, int* __restrict__ row_off,
                        float* __restrict__ dinv, int* __restrict__ cursor) {
  int idx = blockIdx.x * 256 + threadIdx.x;
  if (idx < NN) {
    int ro = blockoff[blockIdx.x] + locpre[idx];
    row_off[idx] = ro;
    cursor[idx] = ro;
    dinv[idx] = rsqrtf((float)(indeg[idx] + 1));  // +1 self-loop
  }
}

__global__ void k_fill(const int* __restrict__ src, const int* __restrict__ dst,
                       int* __restrict__ cursor, int* __restrict__ csr_src) {
  int e = blockIdx.x * 256 + threadIdx.x;
  if (e < NE) {
    int pos = atomicAdd(&cursor[dst[e]], 1);
    csr_src[pos] = src[e];
  }
}

// ---------- dense: g[i][:] = dinv[i] * (h[i][:] @ W) ----------
// 64 rows x 128 cols per 256-thread block. LDS-staged h and W; thread tile
// 4 rows x 8 cols; k-unroll 4 (full unroll spilled: VGPR=256, scratch traffic).

__global__ __launch_bounds__(256) void k_matmul(const float* __restrict__ h,
                                                const float* __restrict__ W,
                                                const float* __restrict__ dinv,
                                                float* __restrict__ g) {
  __shared__ float h_s[64][33];
  __shared__ float w_s[32][128];
  int tid = threadIdx.x;
  int cg = tid & 15;
  int rg = tid >> 4;
  int row0 = blockIdx.x * 64;
  float acc[4][8] = {};

  for (int kc = 0; kc < 4; ++kc) {
#pragma unroll
    for (int i = 0; i < 2; ++i) {
      int idx = tid + 256 * i;
      int r = idx >> 3;
      int o = (idx & 7) * 4;
      int grow = row0 + r;
      if (grow > NN - 1) grow = NN - 1;
      float4 v = *(const float4*)(h + (size_t)grow * FD + kc * 32 + o);
      h_s[r][o + 0] = v.x; h_s[r][o + 1] = v.y;
      h_s[r][o + 2] = v.z; h_s[r][o + 3] = v.w;
    }
#pragma unroll
    for (int i = 0; i < 4; ++i) {
      int p = tid + 256 * i;
      int k = p >> 5;
      int j4 = (p & 31) * 4;
      *(float4*)&w_s[k][j4] = *(const float4*)(W + (size_t)(kc * 32 + k) * FD + j4);
    }
    __syncthreads();

#pragma unroll 4
    for (int k = 0; k < 32; ++k) {
      float4 w0 = *(const float4*)&w_s[k][cg * 8];
      float4 w1 = *(const float4*)&w_s[k][cg * 8 + 4];
#pragma unroll
      for (int rr = 0; rr < 4; ++rr) {
        float hh = h_s[rg * 4 + rr][k];
        acc[rr][0] = fmaf(hh, w0.x, acc[rr][0]);
        acc[rr][1] = fmaf(hh, w0.y, acc[rr][1]);
        acc[rr][2] = fmaf(hh, w0.z, acc[rr][2]);
        acc[rr][3] = fmaf(hh, w0.w, acc[rr][3]);
        acc[rr][4] = fmaf(hh, w1.x, acc[rr][4]);
        acc[rr][5] = fmaf(hh, w1.y, acc[rr][5]);
        acc[rr][6] = fmaf(hh, w1.z, acc[rr][6]);
        acc[rr][7] = fmaf(hh, w1.w, acc[rr][7]);
      }
    }
    __syncthreads();
  }

#pragma unroll
  for (int rr = 0; rr < 4; ++rr) {
    int r = row0 + rg * 4 + rr;
    if (r < NN) {
      float d = dinv[r];
      float4 o1, o2;
      o1.x = acc[rr][0] * d; o1.y = acc[rr][1] * d; o1.z = acc[rr][2] * d; o1.w = acc[rr][3] * d;
      o2.x = acc[rr][4] * d; o2.y = acc[rr][5] * d; o2.z = acc[rr][6] * d; o2.w = acc[rr][7] * d;
      *(float4*)(g + (size_t)r * FD + cg * 8) = o1;
      *(float4*)(g + (size_t)r * FD + cg * 8 + 4) = o2;
    }
  }
}

// ---------- sparse aggregate ----------

__global__ __launch_bounds__(256) void k_agg(const float* __restrict__ g,
                                             const int* __restrict__ row_off,
                                             const int* __restrict__ csr_src,
                                             const float* __restrict__ dinv,
                                             const float* __restrict__ bias,
                                             float* __restrict__ out) {
  int node = blockIdx.x * 8 + (threadIdx.x >> 5);
  int f4 = threadIdx.x & 31;
  if (node >= NN) return;
  const float4* gp = (const float4*)g;
  float4 self = gp[(size_t)node * 32 + f4];
  float a0 = self.x, a1 = self.y, a2 = self.z, a3 = self.w;
  float b0 = 0.f, b1 = 0.f, b2 = 0.f, b3 = 0.f;
  int e0 = row_off[node], e1 = row_off[node + 1];
  int e = e0;
  for (; e + 4 <= e1; e += 4) {
    int s0 = csr_src[e + 0];
    int s1 = csr_src[e + 1];
    int s2 = csr_src[e + 2];
    int s3 = csr_src[e + 3];
    float4 v0 = gp[(size_t)s0 * 32 + f4];
    float4 v1 = gp[(size_t)s1 * 32 + f4];
    float4 v2 = gp[(size_t)s2 * 32 + f4];
    float4 v3 = gp[(size_t)s3 * 32 + f4];
    a0 += v0.x + v1.x; a1 += v0.y + v1.y; a2 += v0.z + v1.z; a3 += v0.w + v1.w;
    b0 += v2.x + v3.x; b1 += v2.y + v3.y; b2 += v2.z + v3.z; b3 += v2.w + v3.w;
  }
  for (; e < e1; ++e) {
    int s = csr_src[e];
    float4 v = gp[(size_t)s * 32 + f4];
    a0 += v.x; a1 += v.y; a2 += v.z; a3 += v.w;
  }
  float d = dinv[node];
  float4 bv = ((const float4*)bias)[f4];
  float4 o;
  o.x = fmaxf(d * (a0 + b0) + bv.x, 0.f);
  o.y = fmaxf(d * (a1 + b1) + bv.y, 0.f);
  o.z = fmaxf(d * (a2 + b2) + bv.z, 0.f);
  o.w = fmaxf(d * (a3 + b3) + bv.w, 0.f);
  *(float4*)(out + (size_t)node * FD + f4 * 4) = o;
}

// ---------- pooling ----------

__global__ void k_pool(const float* __restrict__ h, const int* __restrict__ batch,
                       float* __restrict__ addp, float* __restrict__ cnt,
                       unsigned int* __restrict__ maxp) {
  const int PN = 64;
  int f = threadIdx.x;  // 0..127
  int n0 = blockIdx.x * PN;
  if (n0 >= NN) return;
  int n1 = n0 + PN; if (n1 > NN) n1 = NN;
  int curg = batch[n0];
  float s = 0.f, m = 0.f;
  int c = 0;
  for (int n = n0; n < n1; ++n) {
    int gi = batch[n];
    if (gi != curg) {
      atomicAdd(&addp[curg * FD + f], s);
      atomicMax(&maxp[curg * FD + f], __float_as_uint(m));
      if (f == 0) atomicAdd(&cnt[curg], (float)c);
      s = 0.f; m = 0.f; c = 0; curg = gi;
    }
    float v = h[(size_t)n * FD + f];
    s += v;
    m = fmaxf(m, v);
    c += 1;
  }
  atomicAdd(&addp[curg * FD + f], s);
  atomicMax(&maxp[curg * FD + f], __float_as_uint(m));  // h >= 0 post-relu
  if (f == 0) atomicAdd(&cnt[curg], (float)c);
}

// ---------- enc assembly + 2-layer MLP ----------

__global__ void k_final(const float* __restrict__ addp, const float* __restrict__ cnt,
                        const unsigned int* __restrict__ maxp,
                        const float* __restrict__ l1w, const float* __restrict__ l1b,
                        const float* __restrict__ l2w, const float* __restrict__ l2b,
                        float* __restrict__ d_out) {
  __shared__ float enc_s[384];
  __shared__ float hid_s[128];
  int gph = blockIdx.x, j = threadIdx.x;
  float a = addp[gph * FD + j];
  float c = cnt[gph];
  float mn = a / fmaxf(c, 1.f);
  float mx = __uint_as_float(maxp[gph * FD + j]);
  enc_s[j] = a; enc_s[128 + j] = mn; enc_s[256 + j] = mx;
  float* enc_out = d_out + 2 * NG;
  enc_out[gph * 384 + j] = a;
  enc_out[gph * 384 + 128 + j] = mn;
  enc_out[gph * 384 + 256 + j] = mx;
  __syncthreads();
  float sacc = l1b[j];
  for (int k = 0; k < 384; ++k) sacc = fmaf(enc_s[k], l1w[k * FD + j], sacc);
  hid_s[j] = fmaxf(sacc, 0.f);
  __syncthreads();
  if (j < 2) {
    float o = l2b[j];
    for (int k = 0; k < FD; ++k) o = fmaf(hid_s[k], l2w[k * 2 + j], o);
    d_out[gph * 2 + j] = o;
  }
}

extern "C" void kernel_launch(void* const* d_in, const int* in_sizes, int n_in,
                              void* d_out, int out_size, void* d_ws, size_t ws_size,
                              hipStream_t stream) {
  const float* x      = (const float*)d_in[0];
  const int*   edge   = (const int*)d_in[1];
  const int*   batch  = (const int*)d_in[2];
  const float* conv_w = (const float*)d_in[3];
  const float* conv_b = (const float*)d_in[4];
  const float* l1w    = (const float*)d_in[5];
  const float* l1b    = (const float*)d_in[6];
  const float* l2w    = (const float*)d_in[7];
  const float* l2b    = (const float*)d_in[8];
  float* out = (float*)d_out;

  const int* esrc = edge;
  const int* edst = edge + NE;

  char* wsp = (char*)d_ws;
  auto alloc = [&](size_t bytes) -> char* {
    char* p = wsp;
    wsp += (bytes + 255) & ~(size_t)255;
    return p;
  };
  float* bufA    = (float*)alloc(sizeof(float) * NN * FD);
  float* bufB    = (float*)alloc(sizeof(float) * NN * FD);
  int*   csr_src = (int*)alloc(sizeof(int) * NE);
  int*   indeg   = (int*)alloc(sizeof(int) * NN);
  int*   row_off = (int*)alloc(sizeof(int) * (NN + 1));
  int*   cursor  = (int*)alloc(sizeof(int) * NN);
  int*   locpre  = (int*)alloc(sizeof(int) * NN);
  int*   blocksum= (int*)alloc(sizeof(int) * SCAN_NB);
  int*   blockoff= (int*)alloc(sizeof(int) * SCAN_NB);
  float* dinv    = (float*)alloc(sizeof(float) * NN);
  float* addp    = (float*)alloc(sizeof(float) * NG * FD);
  float* cnt     = (float*)alloc(sizeof(float) * NG);
  unsigned int* maxp = (unsigned int*)alloc(sizeof(unsigned int) * NG * FD);

  hipMemsetAsync(indeg, 0, sizeof(int) * NN, stream);
  hipMemsetAsync(addp, 0, sizeof(float) * NG * FD, stream);
  hipMemsetAsync(cnt, 0, sizeof(float) * NG, stream);
  hipMemsetAsync(maxp, 0, sizeof(unsigned int) * NG * FD, stream);

  k_count<<<(NE + 255) / 256, 256, 0, stream>>>(edst, indeg);
  k_scan1<<<SCAN_NB, 256, 0, stream>>>(indeg, locpre, blocksum);
  k_scan2<<<1, 256, 0, stream>>>(blocksum, blockoff, row_off);
  k_scan3<<<SCAN_NB, 256, 0, stream>>>(indeg, locpre, blockoff, row_off, dinv, cursor);
  k_fill<<<(NE + 255) / 256, 256, 0, stream>>>(esrc, edst, cursor, csr_src);

  const float* hin = x;
  for (int l = 0; l < 3; ++l) {
    k_matmul<<<(NN + 63) / 64, 256, 0, stream>>>(hin, conv_w + l * FD * FD, dinv, bufA);
    k_agg<<<(NN + 7) / 8, 256, 0, stream>>>(bufA, row_off, csr_src, dinv, conv_b + l * FD, bufB);
    hin = bufB;
  }

  k_pool<<<(NN + 63) / 64, 128, 0, stream>>>(bufB, batch, addp, cnt, maxp);
  k_final<<<NG, 128, 0, stream>>>(addp, cnt, maxp, l1w, l1b, l2w, l2b, out);
}

// Round 5
// 333.083 us; speedup vs baseline: 11.2334x; 1.2288x over previous
//
#include <hip/hip_runtime.h>

#define NN 50000
#define NE 800000
#define NG 64
#define FD 128
#define SCAN_NB ((NN + 255) / 256)   // 196 scan blocks

typedef unsigned int uint;

// RNE fp32 -> bf16 pair packed into one uint (lo ushort = first elem)
__device__ __forceinline__ uint pack2bf(float a, float b) {
  uint ua = __float_as_uint(a);
  uint ub = __float_as_uint(b);
  ua = (ua + 0x7fffu + ((ua >> 16) & 1u)) >> 16;
  ub = (ub + 0x7fffu + ((ub >> 16) & 1u)) >> 16;
  return ua | (ub << 16);
}

// ---------- CSR build ----------

__global__ void k_count(const int* __restrict__ dst, int* __restrict__ indeg) {
  int e = blockIdx.x * 256 + threadIdx.x;
  if (e < NE) atomicAdd(&indeg[dst[e]], 1);
}

__global__ void k_scan1(const int* __restrict__ indeg, int* __restrict__ locpre,
                        int* __restrict__ blocksum) {
  __shared__ int sums[256];
  int t = threadIdx.x;
  int idx = blockIdx.x * 256 + t;
  int v = (idx < NN) ? indeg[idx] : 0;
  sums[t] = v;
  __syncthreads();
  for (int off = 1; off < 256; off <<= 1) {
    int u = (t >= off) ? sums[t - off] : 0;
    __syncthreads();
    sums[t] += u;
    __syncthreads();
  }
  if (idx < NN) locpre[idx] = sums[t] - v;
  if (t == 255) blocksum[blockIdx.x] = sums[255];
}

__global__ void k_scan2(int* __restrict__ blocksum, int* __restrict__ blockoff,
                        int* __restrict__ row_off) {
  __shared__ int sums[256];
  int t = threadIdx.x;
  int v = (t < SCAN_NB) ? blocksum[t] : 0;
  sums[t] = v;
  __syncthreads();
  for (int off = 1; off < 256; off <<= 1) {
    int u = (t >= off) ? sums[t - off] : 0;
    __syncthreads();
    sums[t] += u;
    __syncthreads();
  }
  if (t < SCAN_NB) blockoff[t] = sums[t] - v;
  if (t == 255) row_off[NN] = sums[255];
}

__global__ void k_scan3(const int* __restrict__ indeg, const int* __restrict__ locpre,
                        const int* __restrict__ blockoff, int* __restrict__ row_off,
                        float* __restrict__ dinv, int* __restrict__ cursor) {
  int idx = blockIdx.x * 256 + threadIdx.x;
  if (idx < NN) {
    int ro = blockoff[blockIdx.x] + locpre[idx];
    row_off[idx] = ro;
    cursor[idx] = ro;
    dinv[idx] = rsqrtf((float)(indeg[idx] + 1));  // +1 self-loop
  }
}

__global__ void k_fill(const int* __restrict__ src, const int* __restrict__ dst,
                       int* __restrict__ cursor, int* __restrict__ csr_src) {
  int e = blockIdx.x * 256 + threadIdx.x;
  if (e < NE) {
    int pos = atomicAdd(&cursor[dst[e]], 1);
    csr_src[pos] = src[e];
  }
}

// ---------- dense: g[i][:] = bf16(dinv[i] * (h[i][:] @ W)) ----------
// 64 rows x 128 cols per 256-thread block; thread tile 4x8; k-unroll 4
// (full unroll spilled at VGPR=256 in R2). Output packed bf16 (RNE).

__global__ __launch_bounds__(256) void k_matmul(const float* __restrict__ h,
                                                const float* __restrict__ W,
                                                const float* __restrict__ dinv,
                                                uint* __restrict__ g16) {
  __shared__ float h_s[64][33];
  __shared__ float w_s[32][128];
  int tid = threadIdx.x;
  int cg = tid & 15;
  int rg = tid >> 4;
  int row0 = blockIdx.x * 64;
  float acc[4][8] = {};

  for (int kc = 0; kc < 4; ++kc) {
#pragma unroll
    for (int i = 0; i < 2; ++i) {
      int idx = tid + 256 * i;
      int r = idx >> 3;
      int o = (idx & 7) * 4;
      int grow = row0 + r;
      if (grow > NN - 1) grow = NN - 1;
      float4 v = *(const float4*)(h + (size_t)grow * FD + kc * 32 + o);
      h_s[r][o + 0] = v.x; h_s[r][o + 1] = v.y;
      h_s[r][o + 2] = v.z; h_s[r][o + 3] = v.w;
    }
#pragma unroll
    for (int i = 0; i < 4; ++i) {
      int p = tid + 256 * i;
      int k = p >> 5;
      int j4 = (p & 31) * 4;
      *(float4*)&w_s[k][j4] = *(const float4*)(W + (size_t)(kc * 32 + k) * FD + j4);
    }
    __syncthreads();

#pragma unroll 4
    for (int k = 0; k < 32; ++k) {
      float4 w0 = *(const float4*)&w_s[k][cg * 8];
      float4 w1 = *(const float4*)&w_s[k][cg * 8 + 4];
#pragma unroll
      for (int rr = 0; rr < 4; ++rr) {
        float hh = h_s[rg * 4 + rr][k];
        acc[rr][0] = fmaf(hh, w0.x, acc[rr][0]);
        acc[rr][1] = fmaf(hh, w0.y, acc[rr][1]);
        acc[rr][2] = fmaf(hh, w0.z, acc[rr][2]);
        acc[rr][3] = fmaf(hh, w0.w, acc[rr][3]);
        acc[rr][4] = fmaf(hh, w1.x, acc[rr][4]);
        acc[rr][5] = fmaf(hh, w1.y, acc[rr][5]);
        acc[rr][6] = fmaf(hh, w1.z, acc[rr][6]);
        acc[rr][7] = fmaf(hh, w1.w, acc[rr][7]);
      }
    }
    __syncthreads();
  }

#pragma unroll
  for (int rr = 0; rr < 4; ++rr) {
    int r = row0 + rg * 4 + rr;
    if (r < NN) {
      float d = dinv[r];
      uint4 o;
      o.x = pack2bf(acc[rr][0] * d, acc[rr][1] * d);
      o.y = pack2bf(acc[rr][2] * d, acc[rr][3] * d);
      o.z = pack2bf(acc[rr][4] * d, acc[rr][5] * d);
      o.w = pack2bf(acc[rr][6] * d, acc[rr][7] * d);
      *(uint4*)(g16 + (size_t)r * (FD / 2) + cg * 4) = o;
    }
  }
}

// ---------- sparse: out[i] = relu(dinv[i]*(sum_{s in N(i)} g[s] + g[i]) + b) ----------
// g is packed bf16: 256B rows. 16 lanes/node (uint4 = 8 bf16 each),
// 16 nodes per 256-thread block, edge loop unrolled x4.

__global__ __launch_bounds__(256) void k_agg(const uint* __restrict__ g16,
                                             const int* __restrict__ row_off,
                                             const int* __restrict__ csr_src,
                                             const float* __restrict__ dinv,
                                             const float* __restrict__ bias,
                                             float* __restrict__ out) {
  int node = blockIdx.x * 16 + (threadIdx.x >> 4);
  int lane = threadIdx.x & 15;
  if (node >= NN) return;
  const uint4* gp = (const uint4*)g16;  // 16 uint4 per row
  float a[8];
  uint4 sv = gp[(size_t)node * 16 + lane];
  a[0] = __uint_as_float(sv.x << 16); a[1] = __uint_as_float(sv.x & 0xffff0000u);
  a[2] = __uint_as_float(sv.y << 16); a[3] = __uint_as_float(sv.y & 0xffff0000u);
  a[4] = __uint_as_float(sv.z << 16); a[5] = __uint_as_float(sv.z & 0xffff0000u);
  a[6] = __uint_as_float(sv.w << 16); a[7] = __uint_as_float(sv.w & 0xffff0000u);

#define ACC8(v)                                                                  \
  a[0] += __uint_as_float(v.x << 16); a[1] += __uint_as_float(v.x & 0xffff0000u); \
  a[2] += __uint_as_float(v.y << 16); a[3] += __uint_as_float(v.y & 0xffff0000u); \
  a[4] += __uint_as_float(v.z << 16); a[5] += __uint_as_float(v.z & 0xffff0000u); \
  a[6] += __uint_as_float(v.w << 16); a[7] += __uint_as_float(v.w & 0xffff0000u);

  int e0 = row_off[node], e1 = row_off[node + 1];
  int e = e0;
  for (; e + 4 <= e1; e += 4) {
    int s0 = csr_src[e + 0];
    int s1 = csr_src[e + 1];
    int s2 = csr_src[e + 2];
    int s3 = csr_src[e + 3];
    uint4 v0 = gp[(size_t)s0 * 16 + lane];
    uint4 v1 = gp[(size_t)s1 * 16 + lane];
    uint4 v2 = gp[(size_t)s2 * 16 + lane];
    uint4 v3 = gp[(size_t)s3 * 16 + lane];
    ACC8(v0) ACC8(v1) ACC8(v2) ACC8(v3)
  }
  for (; e < e1; ++e) {
    int s = csr_src[e];
    uint4 v = gp[(size_t)s * 16 + lane];
    ACC8(v)
  }
#undef ACC8

  float d = dinv[node];
  int f0 = lane * 8;
  float4 b1 = *(const float4*)(bias + f0);
  float4 b2 = *(const float4*)(bias + f0 + 4);
  float4 o1, o2;
  o1.x = fmaxf(fmaf(d, a[0], b1.x), 0.f);
  o1.y = fmaxf(fmaf(d, a[1], b1.y), 0.f);
  o1.z = fmaxf(fmaf(d, a[2], b1.z), 0.f);
  o1.w = fmaxf(fmaf(d, a[3], b1.w), 0.f);
  o2.x = fmaxf(fmaf(d, a[4], b2.x), 0.f);
  o2.y = fmaxf(fmaf(d, a[5], b2.y), 0.f);
  o2.z = fmaxf(fmaf(d, a[6], b2.z), 0.f);
  o2.w = fmaxf(fmaf(d, a[7], b2.w), 0.f);
  *(float4*)(out + (size_t)node * FD + f0) = o1;
  *(float4*)(out + (size_t)node * FD + f0 + 4) = o2;
}

// ---------- pooling ----------

__global__ void k_pool(const float* __restrict__ h, const int* __restrict__ batch,
                       float* __restrict__ addp, float* __restrict__ cnt,
                       unsigned int* __restrict__ maxp) {
  const int PN = 64;
  int f = threadIdx.x;  // 0..127
  int n0 = blockIdx.x * PN;
  if (n0 >= NN) return;
  int n1 = n0 + PN; if (n1 > NN) n1 = NN;
  int curg = batch[n0];
  float s = 0.f, m = 0.f;
  int c = 0;
  for (int n = n0; n < n1; ++n) {
    int gi = batch[n];
    if (gi != curg) {
      atomicAdd(&addp[curg * FD + f], s);
      atomicMax(&maxp[curg * FD + f], __float_as_uint(m));
      if (f == 0) atomicAdd(&cnt[curg], (float)c);
      s = 0.f; m = 0.f; c = 0; curg = gi;
    }
    float v = h[(size_t)n * FD + f];
    s += v;
    m = fmaxf(m, v);
    c += 1;
  }
  atomicAdd(&addp[curg * FD + f], s);
  atomicMax(&maxp[curg * FD + f], __float_as_uint(m));  // h >= 0 post-relu
  if (f == 0) atomicAdd(&cnt[curg], (float)c);
}

// ---------- enc assembly + 2-layer MLP ----------

__global__ void k_final(const float* __restrict__ addp, const float* __restrict__ cnt,
                        const unsigned int* __restrict__ maxp,
                        const float* __restrict__ l1w, const float* __restrict__ l1b,
                        const float* __restrict__ l2w, const float* __restrict__ l2b,
                        float* __restrict__ d_out) {
  __shared__ float enc_s[384];
  __shared__ float hid_s[128];
  int gph = blockIdx.x, j = threadIdx.x;
  float a = addp[gph * FD + j];
  float c = cnt[gph];
  float mn = a / fmaxf(c, 1.f);
  float mx = __uint_as_float(maxp[gph * FD + j]);
  enc_s[j] = a; enc_s[128 + j] = mn; enc_s[256 + j] = mx;
  float* enc_out = d_out + 2 * NG;
  enc_out[gph * 384 + j] = a;
  enc_out[gph * 384 + 128 + j] = mn;
  enc_out[gph * 384 + 256 + j] = mx;
  __syncthreads();
  float sacc = l1b[j];
  for (int k = 0; k < 384; ++k) sacc = fmaf(enc_s[k], l1w[k * FD + j], sacc);
  hid_s[j] = fmaxf(sacc, 0.f);
  __syncthreads();
  if (j < 2) {
    float o = l2b[j];
    for (int k = 0; k < FD; ++k) o = fmaf(hid_s[k], l2w[k * 2 + j], o);
    d_out[gph * 2 + j] = o;
  }
}

extern "C" void kernel_launch(void* const* d_in, const int* in_sizes, int n_in,
                              void* d_out, int out_size, void* d_ws, size_t ws_size,
                              hipStream_t stream) {
  const float* x      = (const float*)d_in[0];
  const int*   edge   = (const int*)d_in[1];
  const int*   batch  = (const int*)d_in[2];
  const float* conv_w = (const float*)d_in[3];
  const float* conv_b = (const float*)d_in[4];
  const float* l1w    = (const float*)d_in[5];
  const float* l1b    = (const float*)d_in[6];
  const float* l2w    = (const float*)d_in[7];
  const float* l2b    = (const float*)d_in[8];
  float* out = (float*)d_out;

  const int* esrc = edge;
  const int* edst = edge + NE;

  char* wsp = (char*)d_ws;
  auto alloc = [&](size_t bytes) -> char* {
    char* p = wsp;
    wsp += (bytes + 255) & ~(size_t)255;
    return p;
  };
  uint*  gbuf    = (uint*)alloc(2u * NN * FD);                 // bf16 g, 12.8 MB
  float* bufB    = (float*)alloc(sizeof(float) * NN * FD);     // fp32 h, 25.6 MB
  int*   csr_src = (int*)alloc(sizeof(int) * NE);
  int*   indeg   = (int*)alloc(sizeof(int) * NN);
  int*   row_off = (int*)alloc(sizeof(int) * (NN + 1));
  int*   cursor  = (int*)alloc(sizeof(int) * NN);
  int*   locpre  = (int*)alloc(sizeof(int) * NN);
  int*   blocksum= (int*)alloc(sizeof(int) * SCAN_NB);
  int*   blockoff= (int*)alloc(sizeof(int) * SCAN_NB);
  float* dinv    = (float*)alloc(sizeof(float) * NN);
  float* addp    = (float*)alloc(sizeof(float) * NG * FD);
  float* cnt     = (float*)alloc(sizeof(float) * NG);
  unsigned int* maxp = (unsigned int*)alloc(sizeof(unsigned int) * NG * FD);

  hipMemsetAsync(indeg, 0, sizeof(int) * NN, stream);
  hipMemsetAsync(addp, 0, sizeof(float) * NG * FD, stream);
  hipMemsetAsync(cnt, 0, sizeof(float) * NG, stream);
  hipMemsetAsync(maxp, 0, sizeof(unsigned int) * NG * FD, stream);

  k_count<<<(NE + 255) / 256, 256, 0, stream>>>(edst, indeg);
  k_scan1<<<SCAN_NB, 256, 0, stream>>>(indeg, locpre, blocksum);
  k_scan2<<<1, 256, 0, stream>>>(blocksum, blockoff, row_off);
  k_scan3<<<SCAN_NB, 256, 0, stream>>>(indeg, locpre, blockoff, row_off, dinv, cursor);
  k_fill<<<(NE + 255) / 256, 256, 0, stream>>>(esrc, edst, cursor, csr_src);

  const float* hin = x;
  for (int l = 0; l < 3; ++l) {
    k_matmul<<<(NN + 63) / 64, 256, 0, stream>>>(hin, conv_w + l * FD * FD, dinv, gbuf);
    k_agg<<<(NN + 15) / 16, 256, 0, stream>>>(gbuf, row_off, csr_src, dinv, conv_b + l * FD, bufB);
    hin = bufB;
  }

  k_pool<<<(NN + 63) / 64, 128, 0, stream>>>(bufB, batch, addp, cnt, maxp);
  k_final<<<NG, 128, 0, stream>>>(addp, cnt, maxp, l1w, l1b, l2w, l2b, out);
}

// Round 7
// 330.487 us; speedup vs baseline: 11.3216x; 1.0079x over previous
//
#include <hip/hip_runtime.h>

#define NN 50000
#define NE 800000
#define NG 64
#define FD 128
#define SCAN_NB ((NN + 255) / 256)   // 196 scan blocks

typedef unsigned int uint;

// RNE fp32 -> bf16 pair packed into one uint (lo ushort = first elem)
__device__ __forceinline__ uint pack2bf(float a, float b) {
  uint ua = __float_as_uint(a);
  uint ub = __float_as_uint(b);
  ua = (ua + 0x7fffu + ((ua >> 16) & 1u)) >> 16;
  ub = (ub + 0x7fffu + ((ub >> 16) & 1u)) >> 16;
  return ua | (ub << 16);
}

#define BFLO(u) __uint_as_float((u) << 16)
#define BFHI(u) __uint_as_float((u) & 0xffff0000u)

// ---------- CSR build ----------

__global__ void k_count(const int* __restrict__ dst, int* __restrict__ indeg) {
  int i = blockIdx.x * 256 + threadIdx.x;          // NE/4 = 200000 threads
  if (i < NE / 4) {
    int4 d = ((const int4*)dst)[i];
    atomicAdd(&indeg[d.x], 1);
    atomicAdd(&indeg[d.y], 1);
    atomicAdd(&indeg[d.z], 1);
    atomicAdd(&indeg[d.w], 1);
  }
}

__global__ void k_scan1(const int* __restrict__ indeg, int* __restrict__ locpre,
                        int* __restrict__ blocksum) {
  __shared__ int sums[256];
  int t = threadIdx.x;
  int idx = blockIdx.x * 256 + t;
  int v = (idx < NN) ? indeg[idx] : 0;
  sums[t] = v;
  __syncthreads();
  for (int off = 1; off < 256; off <<= 1) {
    int u = (t >= off) ? sums[t - off] : 0;
    __syncthreads();
    sums[t] += u;
    __syncthreads();
  }
  if (idx < NN) locpre[idx] = sums[t] - v;
  if (t == 255) blocksum[blockIdx.x] = sums[255];
}

__global__ void k_scan2(int* __restrict__ blocksum, int* __restrict__ blockoff,
                        int* __restrict__ row_off) {
  __shared__ int sums[256];
  int t = threadIdx.x;
  int v = (t < SCAN_NB) ? blocksum[t] : 0;
  sums[t] = v;
  __syncthreads();
  for (int off = 1; off < 256; off <<= 1) {
    int u = (t >= off) ? sums[t - off] : 0;
    __syncthreads();
    sums[t] += u;
    __syncthreads();
  }
  if (t < SCAN_NB) blockoff[t] = sums[t] - v;
  if (t == 255) row_off[NN] = sums[255];
}

__global__ void k_scan3(const int* __restrict__ indeg, const int* __restrict__ locpre,
                        const int* __restrict__ blockoff, int* __restrict__ row_off,
                        float* __restrict__ dinv, int* __restrict__ cursor) {
  int idx = blockIdx.x * 256 + threadIdx.x;
  if (idx < NN) {
    int ro = blockoff[blockIdx.x] + locpre[idx];
    row_off[idx] = ro;
    cursor[idx] = ro;
    dinv[idx] = rsqrtf((float)(indeg[idx] + 1));  // +1 self-loop
  }
}

__global__ void k_fill(const int* __restrict__ src, const int* __restrict__ dst,
                       int* __restrict__ cursor, int* __restrict__ csr_src) {
  int i = blockIdx.x * 256 + threadIdx.x;          // NE/4 threads
  if (i < NE / 4) {
    int4 s = ((const int4*)src)[i];
    int4 d = ((const int4*)dst)[i];
    int p0 = atomicAdd(&cursor[d.x], 1);
    int p1 = atomicAdd(&cursor[d.y], 1);
    int p2 = atomicAdd(&cursor[d.z], 1);
    int p3 = atomicAdd(&cursor[d.w], 1);
    csr_src[p0] = s.x;
    csr_src[p1] = s.y;
    csr_src[p2] = s.z;
    csr_src[p3] = s.w;
  }
}

// ---------- dense (layer 0, fp32 input): g = bf16(dinv * (x @ W)) ----------
// 64 rows x 128 cols per 256-thread block; thread tile 4x8; k-unroll 4.

__global__ __launch_bounds__(256) void k_matmul_f32(const float* __restrict__ h,
                                                    const float* __restrict__ W,
                                                    const float* __restrict__ dinv,
                                                    uint* __restrict__ g16) {
  __shared__ float h_s[64][33];
  __shared__ float w_s[32][128];
  int tid = threadIdx.x;
  int cg = tid & 15;
  int rg = tid >> 4;
  int row0 = blockIdx.x * 64;
  float acc[4][8] = {};

  for (int kc = 0; kc < 4; ++kc) {
#pragma unroll
    for (int i = 0; i < 2; ++i) {
      int idx = tid + 256 * i;
      int r = idx >> 3;
      int o = (idx & 7) * 4;
      int grow = row0 + r;
      if (grow > NN - 1) grow = NN - 1;
      float4 v = *(const float4*)(h + (size_t)grow * FD + kc * 32 + o);
      h_s[r][o + 0] = v.x; h_s[r][o + 1] = v.y;
      h_s[r][o + 2] = v.z; h_s[r][o + 3] = v.w;
    }
#pragma unroll
    for (int i = 0; i < 4; ++i) {
      int p = tid + 256 * i;
      int k = p >> 5;
      int j4 = (p & 31) * 4;
      *(float4*)&w_s[k][j4] = *(const float4*)(W + (size_t)(kc * 32 + k) * FD + j4);
    }
    __syncthreads();

#pragma unroll 4
    for (int k = 0; k < 32; ++k) {
      float4 w0 = *(const float4*)&w_s[k][cg * 8];
      float4 w1 = *(const float4*)&w_s[k][cg * 8 + 4];
#pragma unroll
      for (int rr = 0; rr < 4; ++rr) {
        float hh = h_s[rg * 4 + rr][k];
        acc[rr][0] = fmaf(hh, w0.x, acc[rr][0]);
        acc[rr][1] = fmaf(hh, w0.y, acc[rr][1]);
        acc[rr][2] = fmaf(hh, w0.z, acc[rr][2]);
        acc[rr][3] = fmaf(hh, w0.w, acc[rr][3]);
        acc[rr][4] = fmaf(hh, w1.x, acc[rr][4]);
        acc[rr][5] = fmaf(hh, w1.y, acc[rr][5]);
        acc[rr][6] = fmaf(hh, w1.z, acc[rr][6]);
        acc[rr][7] = fmaf(hh, w1.w, acc[rr][7]);
      }
    }
    __syncthreads();
  }

#pragma unroll
  for (int rr = 0; rr < 4; ++rr) {
    int r = row0 + rg * 4 + rr;
    if (r < NN) {
      float d = dinv[r];
      uint4 o;
      o.x = pack2bf(acc[rr][0] * d, acc[rr][1] * d);
      o.y = pack2bf(acc[rr][2] * d, acc[rr][3] * d);
      o.z = pack2bf(acc[rr][4] * d, acc[rr][5] * d);
      o.w = pack2bf(acc[rr][6] * d, acc[rr][7] * d);
      *(uint4*)(g16 + (size_t)r * (FD / 2) + cg * 4) = o;
    }
  }
}

// ---------- dense (layers 1..2, bf16 input) ----------

__global__ __launch_bounds__(256) void k_matmul_b16(const uint* __restrict__ h16,
                                                    const float* __restrict__ W,
                                                    const float* __restrict__ dinv,
                                                    uint* __restrict__ g16) {
  __shared__ float h_s[64][33];
  __shared__ float w_s[32][128];
  int tid = threadIdx.x;
  int cg = tid & 15;
  int rg = tid >> 4;
  int row0 = blockIdx.x * 64;
  float acc[4][8] = {};

  for (int kc = 0; kc < 4; ++kc) {
    // stage h rows as bf16: 64 rows x 16 uints; 1 uint4 (8 bf16) per thread
    {
      int r = tid >> 2;
      int o = tid & 3;
      int grow = row0 + r;
      if (grow > NN - 1) grow = NN - 1;
      uint4 u = *(const uint4*)(h16 + (size_t)grow * (FD / 2) + kc * 16 + o * 4);
      float* hd = &h_s[r][o * 8];
      hd[0] = BFLO(u.x); hd[1] = BFHI(u.x);
      hd[2] = BFLO(u.y); hd[3] = BFHI(u.y);
      hd[4] = BFLO(u.z); hd[5] = BFHI(u.z);
      hd[6] = BFLO(u.w); hd[7] = BFHI(u.w);
    }
#pragma unroll
    for (int i = 0; i < 4; ++i) {
      int p = tid + 256 * i;
      int k = p >> 5;
      int j4 = (p & 31) * 4;
      *(float4*)&w_s[k][j4] = *(const float4*)(W + (size_t)(kc * 32 + k) * FD + j4);
    }
    __syncthreads();

#pragma unroll 4
    for (int k = 0; k < 32; ++k) {
      float4 w0 = *(const float4*)&w_s[k][cg * 8];
      float4 w1 = *(const float4*)&w_s[k][cg * 8 + 4];
#pragma unroll
      for (int rr = 0; rr < 4; ++rr) {
        float hh = h_s[rg * 4 + rr][k];
        acc[rr][0] = fmaf(hh, w0.x, acc[rr][0]);
        acc[rr][1] = fmaf(hh, w0.y, acc[rr][1]);
        acc[rr][2] = fmaf(hh, w0.z, acc[rr][2]);
        acc[rr][3] = fmaf(hh, w0.w, acc[rr][3]);
        acc[rr][4] = fmaf(hh, w1.x, acc[rr][4]);
        acc[rr][5] = fmaf(hh, w1.y, acc[rr][5]);
        acc[rr][6] = fmaf(hh, w1.z, acc[rr][6]);
        acc[rr][7] = fmaf(hh, w1.w, acc[rr][7]);
      }
    }
    __syncthreads();
  }

#pragma unroll
  for (int rr = 0; rr < 4; ++rr) {
    int r = row0 + rg * 4 + rr;
    if (r < NN) {
      float d = dinv[r];
      uint4 o;
      o.x = pack2bf(acc[rr][0] * d, acc[rr][1] * d);
      o.y = pack2bf(acc[rr][2] * d, acc[rr][3] * d);
      o.z = pack2bf(acc[rr][4] * d, acc[rr][5] * d);
      o.w = pack2bf(acc[rr][6] * d, acc[rr][7] * d);
      *(uint4*)(g16 + (size_t)r * (FD / 2) + cg * 4) = o;
    }
  }
}

// ---------- sparse: h' = bf16(relu(dinv*(sum g[s] + g[node]) + b)) ----------

__global__ __launch_bounds__(256) void k_agg(const uint* __restrict__ g16,
                                             const int* __restrict__ row_off,
                                             const int* __restrict__ csr_src,
                                             const float* __restrict__ dinv,
                                             const float* __restrict__ bias,
                                             uint* __restrict__ out16) {
  int node = blockIdx.x * 16 + (threadIdx.x >> 4);
  int lane = threadIdx.x & 15;
  if (node >= NN) return;
  const uint4* gp = (const uint4*)g16;  // 16 uint4 per row
  float a[8];
  uint4 sv = gp[(size_t)node * 16 + lane];
  a[0] = BFLO(sv.x); a[1] = BFHI(sv.x);
  a[2] = BFLO(sv.y); a[3] = BFHI(sv.y);
  a[4] = BFLO(sv.z); a[5] = BFHI(sv.z);
  a[6] = BFLO(sv.w); a[7] = BFHI(sv.w);

#define ACC8(v)                                      \
  a[0] += BFLO(v.x); a[1] += BFHI(v.x);              \
  a[2] += BFLO(v.y); a[3] += BFHI(v.y);              \
  a[4] += BFLO(v.z); a[5] += BFHI(v.z);              \
  a[6] += BFLO(v.w); a[7] += BFHI(v.w);

  int e0 = row_off[node], e1 = row_off[node + 1];
  int e = e0;
  for (; e + 4 <= e1; e += 4) {
    int s0 = csr_src[e + 0];
    int s1 = csr_src[e + 1];
    int s2 = csr_src[e + 2];
    int s3 = csr_src[e + 3];
    uint4 v0 = gp[(size_t)s0 * 16 + lane];
    uint4 v1 = gp[(size_t)s1 * 16 + lane];
    uint4 v2 = gp[(size_t)s2 * 16 + lane];
    uint4 v3 = gp[(size_t)s3 * 16 + lane];
    ACC8(v0) ACC8(v1) ACC8(v2) ACC8(v3)
  }
  for (; e < e1; ++e) {
    int s = csr_src[e];
    uint4 v = gp[(size_t)s * 16 + lane];
    ACC8(v)
  }
#undef ACC8

  float d = dinv[node];
  int f0 = lane * 8;
  float4 b1 = *(const float4*)(bias + f0);
  float4 b2 = *(const float4*)(bias + f0 + 4);
  float o0 = fmaxf(fmaf(d, a[0], b1.x), 0.f);
  float o1 = fmaxf(fmaf(d, a[1], b1.y), 0.f);
  float o2 = fmaxf(fmaf(d, a[2], b1.z), 0.f);
  float o3 = fmaxf(fmaf(d, a[3], b1.w), 0.f);
  float o4 = fmaxf(fmaf(d, a[4], b2.x), 0.f);
  float o5 = fmaxf(fmaf(d, a[5], b2.y), 0.f);
  float o6 = fmaxf(fmaf(d, a[6], b2.z), 0.f);
  float o7 = fmaxf(fmaf(d, a[7], b2.w), 0.f);
  uint4 ov;
  ov.x = pack2bf(o0, o1);
  ov.y = pack2bf(o2, o3);
  ov.z = pack2bf(o4, o5);
  ov.w = pack2bf(o6, o7);
  *(uint4*)(out16 + (size_t)node * (FD / 2) + lane * 4) = ov;
}

// ---------- pooling (bf16 h input; batch sorted -> run-length accumulate) ----------
// 64 threads/block: thread f handles the uint f = feature pair (2f, 2f+1).

__global__ void k_pool(const uint* __restrict__ h16, const int* __restrict__ batch,
                       float* __restrict__ addp, float* __restrict__ cnt,
                       unsigned int* __restrict__ maxp) {
  const int PN = 64;
  int f = threadIdx.x;  // 0..63 -> features (2f, 2f+1)
  int n0 = blockIdx.x * PN;
  if (n0 >= NN) return;
  int n1 = n0 + PN; if (n1 > NN) n1 = NN;
  int curg = batch[n0];
  float s0 = 0.f, s1 = 0.f, m0 = 0.f, m1 = 0.f;
  int c = 0;
  for (int n = n0; n < n1; ++n) {
    int gi = batch[n];
    if (gi != curg) {
      atomicAdd(&addp[curg * FD + 2 * f], s0);
      atomicAdd(&addp[curg * FD + 2 * f + 1], s1);
      atomicMax(&maxp[curg * FD + 2 * f], __float_as_uint(m0));
      atomicMax(&maxp[curg * FD + 2 * f + 1], __float_as_uint(m1));
      if (f == 0) atomicAdd(&cnt[curg], (float)c);
      s0 = 0.f; s1 = 0.f; m0 = 0.f; m1 = 0.f; c = 0; curg = gi;
    }
    uint u = h16[(size_t)n * (FD / 2) + f];
    float lo = BFLO(u), hi = BFHI(u);
    s0 += lo; s1 += hi;
    m0 = fmaxf(m0, lo); m1 = fmaxf(m1, hi);
    c += 1;
  }
  atomicAdd(&addp[curg * FD + 2 * f], s0);
  atomicAdd(&addp[curg * FD + 2 * f + 1], s1);
  atomicMax(&maxp[curg * FD + 2 * f], __float_as_uint(m0));   // h >= 0 post-relu
  atomicMax(&maxp[curg * FD + 2 * f + 1], __float_as_uint(m1));
  if (f == 0) atomicAdd(&cnt[curg], (float)c);
}

// ---------- enc assembly + 2-layer MLP ----------

__global__ void k_final(const float* __restrict__ addp, const float* __restrict__ cnt,
                        const unsigned int* __restrict__ maxp,
                        const float* __restrict__ l1w, const float* __restrict__ l1b,
                        const float* __restrict__ l2w, const float* __restrict__ l2b,
                        float* __restrict__ d_out) {
  __shared__ float enc_s[384];
  __shared__ float hid_s[128];
  int gph = blockIdx.x, j = threadIdx.x;
  float a = addp[gph * FD + j];
  float c = cnt[gph];
  float mn = a / fmaxf(c, 1.f);
  float mx = __uint_as_float(maxp[gph * FD + j]);
  enc_s[j] = a; enc_s[128 + j] = mn; enc_s[256 + j] = mx;
  float* enc_out = d_out + 2 * NG;
  enc_out[gph * 384 + j] = a;
  enc_out[gph * 384 + 128 + j] = mn;
  enc_out[gph * 384 + 256 + j] = mx;
  __syncthreads();
  float sacc = l1b[j];
  for (int k = 0; k < 384; ++k) sacc = fmaf(enc_s[k], l1w[k * FD + j], sacc);
  hid_s[j] = fmaxf(sacc, 0.f);
  __syncthreads();
  if (j < 2) {
    float o = l2b[j];
    for (int k = 0; k < FD; ++k) o = fmaf(hid_s[k], l2w[k * 2 + j], o);
    d_out[gph * 2 + j] = o;
  }
}

extern "C" void kernel_launch(void* const* d_in, const int* in_sizes, int n_in,
                              void* d_out, int out_size, void* d_ws, size_t ws_size,
                              hipStream_t stream) {
  const float* x      = (const float*)d_in[0];
  const int*   edge   = (const int*)d_in[1];
  const int*   batch  = (const int*)d_in[2];
  const float* conv_w = (const float*)d_in[3];
  const float* conv_b = (const float*)d_in[4];
  const float* l1w    = (const float*)d_in[5];
  const float* l1b    = (const float*)d_in[6];
  const float* l2w    = (const float*)d_in[7];
  const float* l2b    = (const float*)d_in[8];
  float* out = (float*)d_out;

  const int* esrc = edge;
  const int* edst = edge + NE;

  char* wsp = (char*)d_ws;
  auto alloc = [&](size_t bytes) -> char* {
    char* p = wsp;
    wsp += (bytes + 255) & ~(size_t)255;
    return p;
  };
  uint*  gbuf    = (uint*)alloc(2u * NN * FD);   // bf16 g, 12.8 MB
  uint*  hbuf    = (uint*)alloc(2u * NN * FD);   // bf16 h, 12.8 MB
  int*   csr_src = (int*)alloc(sizeof(int) * NE);
  int*   indeg   = (int*)alloc(sizeof(int) * NN);
  int*   row_off = (int*)alloc(sizeof(int) * (NN + 1));
  int*   cursor  = (int*)alloc(sizeof(int) * NN);
  int*   locpre  = (int*)alloc(sizeof(int) * NN);
  int*   blocksum= (int*)alloc(sizeof(int) * SCAN_NB);
  int*   blockoff= (int*)alloc(sizeof(int) * SCAN_NB);
  float* dinv    = (float*)alloc(sizeof(float) * NN);
  float* addp    = (float*)alloc(sizeof(float) * NG * FD);
  float* cnt     = (float*)alloc(sizeof(float) * NG);
  unsigned int* maxp = (unsigned int*)alloc(sizeof(unsigned int) * NG * FD);

  hipMemsetAsync(indeg, 0, sizeof(int) * NN, stream);
  hipMemsetAsync(addp, 0, sizeof(float) * NG * FD, stream);
  hipMemsetAsync(cnt, 0, sizeof(float) * NG, stream);
  hipMemsetAsync(maxp, 0, sizeof(unsigned int) * NG * FD, stream);

  k_count<<<(NE / 4 + 255) / 256, 256, 0, stream>>>(edst, indeg);
  k_scan1<<<SCAN_NB, 256, 0, stream>>>(indeg, locpre, blocksum);
  k_scan2<<<1, 256, 0, stream>>>(blocksum, blockoff, row_off);
  k_scan3<<<SCAN_NB, 256, 0, stream>>>(indeg, locpre, blockoff, row_off, dinv, cursor);
  k_fill<<<(NE / 4 + 255) / 256, 256, 0, stream>>>(esrc, edst, cursor, csr_src);

  // layer 0 (fp32 x input)
  k_matmul_f32<<<(NN + 63) / 64, 256, 0, stream>>>(x, conv_w + 0 * FD * FD, dinv, gbuf);
  k_agg<<<(NN + 15) / 16, 256, 0, stream>>>(gbuf, row_off, csr_src, dinv, conv_b + 0 * FD, hbuf);
  // layers 1..2 (bf16 h input)
  for (int l = 1; l < 3; ++l) {
    k_matmul_b16<<<(NN + 63) / 64, 256, 0, stream>>>(hbuf, conv_w + l * FD * FD, dinv, gbuf);
    k_agg<<<(NN + 15) / 16, 256, 0, stream>>>(gbuf, row_off, csr_src, dinv, conv_b + l * FD, hbuf);
  }

  k_pool<<<(NN + 63) / 64, 64, 0, stream>>>(hbuf, batch, addp, cnt, maxp);
  k_final<<<NG, 128, 0, stream>>>(addp, cnt, maxp, l1w, l1b, l2w, l2b, out);
}

// Round 8
// 316.125 us; speedup vs baseline: 11.8360x; 1.0454x over previous
//
#include <hip/hip_runtime.h>

#define NN 50000
#define NE 800000
#define NG 64
#define FD 128
#define SCAN_NB ((NN + 255) / 256)   // 196 scan blocks
#define NROLE 8                      // XCD count heuristic (blockIdx % 8)
#define NCHUNK 98                    // edge chunks per role
#define NODES_PER_ROLE (NN / NROLE)  // 6250 exactly

typedef unsigned int uint;

// RNE fp32 -> bf16 pair packed into one uint (lo ushort = first elem)
__device__ __forceinline__ uint pack2bf(float a, float b) {
  uint ua = __float_as_uint(a);
  uint ub = __float_as_uint(b);
  ua = (ua + 0x7fffu + ((ua >> 16) & 1u)) >> 16;
  ub = (ub + 0x7fffu + ((ub >> 16) & 1u)) >> 16;
  return ua | (ub << 16);
}

#define BFLO(u) __uint_as_float((u) << 16)
#define BFHI(u) __uint_as_float((u) & 0xffff0000u)

// ---------- workspace zeroing (replaces 4 memsets) ----------

__global__ void k_zero(int* __restrict__ indeg, float* __restrict__ addp,
                       float* __restrict__ cnt, uint* __restrict__ maxp) {
  int i = blockIdx.x * 256 + threadIdx.x;
  if (i < NN) indeg[i] = 0;
  if (i < NG * FD) { addp[i] = 0.f; maxp[i] = 0u; }
  if (i < NG) cnt[i] = 0.f;
}

// ---------- CSR build ----------
// XCD-sharded: role = blockIdx & 7 handles only dst in its node range, so
// cursor lines and csr_src lines stay in one XCD's L2 (kills the 16x
// write-back amplification seen at R5-R7: WRITE_SIZE 52MB for 3.2MB payload).

__global__ void k_count(const int* __restrict__ dst, int* __restrict__ indeg) {
  int role = blockIdx.x & (NROLE - 1);
  int chunk = blockIdx.x >> 3;
  int lo = role * NODES_PER_ROLE, hi = lo + NODES_PER_ROLE;
  for (int i = chunk * 256 + threadIdx.x; i < NE / 4; i += NCHUNK * 256) {
    int4 d = ((const int4*)dst)[i];
    if (d.x >= lo && d.x < hi) atomicAdd(&indeg[d.x], 1);
    if (d.y >= lo && d.y < hi) atomicAdd(&indeg[d.y], 1);
    if (d.z >= lo && d.z < hi) atomicAdd(&indeg[d.z], 1);
    if (d.w >= lo && d.w < hi) atomicAdd(&indeg[d.w], 1);
  }
}

__global__ void k_scan1(const int* __restrict__ indeg, int* __restrict__ locpre,
                        int* __restrict__ blocksum) {
  __shared__ int sums[256];
  int t = threadIdx.x;
  int idx = blockIdx.x * 256 + t;
  int v = (idx < NN) ? indeg[idx] : 0;
  sums[t] = v;
  __syncthreads();
  for (int off = 1; off < 256; off <<= 1) {
    int u = (t >= off) ? sums[t - off] : 0;
    __syncthreads();
    sums[t] += u;
    __syncthreads();
  }
  if (idx < NN) locpre[idx] = sums[t] - v;
  if (t == 255) blocksum[blockIdx.x] = sums[255];
}

__global__ void k_scan2(int* __restrict__ blocksum, int* __restrict__ blockoff,
                        int* __restrict__ row_off) {
  __shared__ int sums[256];
  int t = threadIdx.x;
  int v = (t < SCAN_NB) ? blocksum[t] : 0;
  sums[t] = v;
  __syncthreads();
  for (int off = 1; off < 256; off <<= 1) {
    int u = (t >= off) ? sums[t - off] : 0;
    __syncthreads();
    sums[t] += u;
    __syncthreads();
  }
  if (t < SCAN_NB) blockoff[t] = sums[t] - v;
  if (t == 255) row_off[NN] = sums[255];
}

__global__ void k_scan3(const int* __restrict__ indeg, const int* __restrict__ locpre,
                        const int* __restrict__ blockoff, int* __restrict__ row_off,
                        float* __restrict__ dinv, int* __restrict__ cursor) {
  int idx = blockIdx.x * 256 + threadIdx.x;
  if (idx < NN) {
    int ro = blockoff[blockIdx.x] + locpre[idx];
    row_off[idx] = ro;
    cursor[idx] = ro;
    dinv[idx] = rsqrtf((float)(indeg[idx] + 1));  // +1 self-loop
  }
}

__global__ void k_fill(const int* __restrict__ src, const int* __restrict__ dst,
                       int* __restrict__ cursor, int* __restrict__ csr_src) {
  int role = blockIdx.x & (NROLE - 1);
  int chunk = blockIdx.x >> 3;
  int lo = role * NODES_PER_ROLE, hi = lo + NODES_PER_ROLE;
  for (int i = chunk * 256 + threadIdx.x; i < NE / 4; i += NCHUNK * 256) {
    int4 s = ((const int4*)src)[i];
    int4 d = ((const int4*)dst)[i];
    if (d.x >= lo && d.x < hi) { int p = atomicAdd(&cursor[d.x], 1); csr_src[p] = s.x; }
    if (d.y >= lo && d.y < hi) { int p = atomicAdd(&cursor[d.y], 1); csr_src[p] = s.y; }
    if (d.z >= lo && d.z < hi) { int p = atomicAdd(&cursor[d.z], 1); csr_src[p] = s.z; }
    if (d.w >= lo && d.w < hi) { int p = atomicAdd(&cursor[d.w], 1); csr_src[p] = s.w; }
  }
}

// ---------- dense (layer 0, fp32 input): g = bf16(dinv * (x @ W)) ----------

__global__ __launch_bounds__(256) void k_matmul_f32(const float* __restrict__ h,
                                                    const float* __restrict__ W,
                                                    const float* __restrict__ dinv,
                                                    uint* __restrict__ g16) {
  __shared__ float h_s[64][33];
  __shared__ float w_s[32][128];
  int tid = threadIdx.x;
  int cg = tid & 15;
  int rg = tid >> 4;
  int row0 = blockIdx.x * 64;
  float acc[4][8] = {};

  for (int kc = 0; kc < 4; ++kc) {
#pragma unroll
    for (int i = 0; i < 2; ++i) {
      int idx = tid + 256 * i;
      int r = idx >> 3;
      int o = (idx & 7) * 4;
      int grow = row0 + r;
      if (grow > NN - 1) grow = NN - 1;
      float4 v = *(const float4*)(h + (size_t)grow * FD + kc * 32 + o);
      h_s[r][o + 0] = v.x; h_s[r][o + 1] = v.y;
      h_s[r][o + 2] = v.z; h_s[r][o + 3] = v.w;
    }
#pragma unroll
    for (int i = 0; i < 4; ++i) {
      int p = tid + 256 * i;
      int k = p >> 5;
      int j4 = (p & 31) * 4;
      *(float4*)&w_s[k][j4] = *(const float4*)(W + (size_t)(kc * 32 + k) * FD + j4);
    }
    __syncthreads();

#pragma unroll 4
    for (int k = 0; k < 32; ++k) {
      float4 w0 = *(const float4*)&w_s[k][cg * 8];
      float4 w1 = *(const float4*)&w_s[k][cg * 8 + 4];
#pragma unroll
      for (int rr = 0; rr < 4; ++rr) {
        float hh = h_s[rg * 4 + rr][k];
        acc[rr][0] = fmaf(hh, w0.x, acc[rr][0]);
        acc[rr][1] = fmaf(hh, w0.y, acc[rr][1]);
        acc[rr][2] = fmaf(hh, w0.z, acc[rr][2]);
        acc[rr][3] = fmaf(hh, w0.w, acc[rr][3]);
        acc[rr][4] = fmaf(hh, w1.x, acc[rr][4]);
        acc[rr][5] = fmaf(hh, w1.y, acc[rr][5]);
        acc[rr][6] = fmaf(hh, w1.z, acc[rr][6]);
        acc[rr][7] = fmaf(hh, w1.w, acc[rr][7]);
      }
    }
    __syncthreads();
  }

#pragma unroll
  for (int rr = 0; rr < 4; ++rr) {
    int r = row0 + rg * 4 + rr;
    if (r < NN) {
      float d = dinv[r];
      uint4 o;
      o.x = pack2bf(acc[rr][0] * d, acc[rr][1] * d);
      o.y = pack2bf(acc[rr][2] * d, acc[rr][3] * d);
      o.z = pack2bf(acc[rr][4] * d, acc[rr][5] * d);
      o.w = pack2bf(acc[rr][6] * d, acc[rr][7] * d);
      *(uint4*)(g16 + (size_t)r * (FD / 2) + cg * 4) = o;
    }
  }
}

// ---------- dense (layers 1..2, bf16 input) ----------

__global__ __launch_bounds__(256) void k_matmul_b16(const uint* __restrict__ h16,
                                                    const float* __restrict__ W,
                                                    const float* __restrict__ dinv,
                                                    uint* __restrict__ g16) {
  __shared__ float h_s[64][33];
  __shared__ float w_s[32][128];
  int tid = threadIdx.x;
  int cg = tid & 15;
  int rg = tid >> 4;
  int row0 = blockIdx.x * 64;
  float acc[4][8] = {};

  for (int kc = 0; kc < 4; ++kc) {
    {
      int r = tid >> 2;
      int o = tid & 3;
      int grow = row0 + r;
      if (grow > NN - 1) grow = NN - 1;
      uint4 u = *(const uint4*)(h16 + (size_t)grow * (FD / 2) + kc * 16 + o * 4);
      float* hd = &h_s[r][o * 8];
      hd[0] = BFLO(u.x); hd[1] = BFHI(u.x);
      hd[2] = BFLO(u.y); hd[3] = BFHI(u.y);
      hd[4] = BFLO(u.z); hd[5] = BFHI(u.z);
      hd[6] = BFLO(u.w); hd[7] = BFHI(u.w);
    }
#pragma unroll
    for (int i = 0; i < 4; ++i) {
      int p = tid + 256 * i;
      int k = p >> 5;
      int j4 = (p & 31) * 4;
      *(float4*)&w_s[k][j4] = *(const float4*)(W + (size_t)(kc * 32 + k) * FD + j4);
    }
    __syncthreads();

#pragma unroll 4
    for (int k = 0; k < 32; ++k) {
      float4 w0 = *(const float4*)&w_s[k][cg * 8];
      float4 w1 = *(const float4*)&w_s[k][cg * 8 + 4];
#pragma unroll
      for (int rr = 0; rr < 4; ++rr) {
        float hh = h_s[rg * 4 + rr][k];
        acc[rr][0] = fmaf(hh, w0.x, acc[rr][0]);
        acc[rr][1] = fmaf(hh, w0.y, acc[rr][1]);
        acc[rr][2] = fmaf(hh, w0.z, acc[rr][2]);
        acc[rr][3] = fmaf(hh, w0.w, acc[rr][3]);
        acc[rr][4] = fmaf(hh, w1.x, acc[rr][4]);
        acc[rr][5] = fmaf(hh, w1.y, acc[rr][5]);
        acc[rr][6] = fmaf(hh, w1.z, acc[rr][6]);
        acc[rr][7] = fmaf(hh, w1.w, acc[rr][7]);
      }
    }
    __syncthreads();
  }

#pragma unroll
  for (int rr = 0; rr < 4; ++rr) {
    int r = row0 + rg * 4 + rr;
    if (r < NN) {
      float d = dinv[r];
      uint4 o;
      o.x = pack2bf(acc[rr][0] * d, acc[rr][1] * d);
      o.y = pack2bf(acc[rr][2] * d, acc[rr][3] * d);
      o.z = pack2bf(acc[rr][4] * d, acc[rr][5] * d);
      o.w = pack2bf(acc[rr][6] * d, acc[rr][7] * d);
      *(uint4*)(g16 + (size_t)r * (FD / 2) + cg * 4) = o;
    }
  }
}

// ---------- sparse: h' = bf16(relu(dinv*(sum g[s] + g[node]) + b)) ----------

__global__ __launch_bounds__(256) void k_agg(const uint* __restrict__ g16,
                                             const int* __restrict__ row_off,
                                             const int* __restrict__ csr_src,
                                             const float* __restrict__ dinv,
                                             const float* __restrict__ bias,
                                             uint* __restrict__ out16) {
  int node = blockIdx.x * 16 + (threadIdx.x >> 4);
  int lane = threadIdx.x & 15;
  if (node >= NN) return;
  const uint4* gp = (const uint4*)g16;  // 16 uint4 per row
  float a[8];
  uint4 sv = gp[(size_t)node * 16 + lane];
  a[0] = BFLO(sv.x); a[1] = BFHI(sv.x);
  a[2] = BFLO(sv.y); a[3] = BFHI(sv.y);
  a[4] = BFLO(sv.z); a[5] = BFHI(sv.z);
  a[6] = BFLO(sv.w); a[7] = BFHI(sv.w);

#define ACC8(v)                                      \
  a[0] += BFLO(v.x); a[1] += BFHI(v.x);              \
  a[2] += BFLO(v.y); a[3] += BFHI(v.y);              \
  a[4] += BFLO(v.z); a[5] += BFHI(v.z);              \
  a[6] += BFLO(v.w); a[7] += BFHI(v.w);

  int e0 = row_off[node], e1 = row_off[node + 1];
  int e = e0;
  for (; e + 4 <= e1; e += 4) {
    int s0 = csr_src[e + 0];
    int s1 = csr_src[e + 1];
    int s2 = csr_src[e + 2];
    int s3 = csr_src[e + 3];
    uint4 v0 = gp[(size_t)s0 * 16 + lane];
    uint4 v1 = gp[(size_t)s1 * 16 + lane];
    uint4 v2 = gp[(size_t)s2 * 16 + lane];
    uint4 v3 = gp[(size_t)s3 * 16 + lane];
    ACC8(v0) ACC8(v1) ACC8(v2) ACC8(v3)
  }
  for (; e < e1; ++e) {
    int s = csr_src[e];
    uint4 v = gp[(size_t)s * 16 + lane];
    ACC8(v)
  }
#undef ACC8

  float d = dinv[node];
  int f0 = lane * 8;
  float4 b1 = *(const float4*)(bias + f0);
  float4 b2 = *(const float4*)(bias + f0 + 4);
  float o0 = fmaxf(fmaf(d, a[0], b1.x), 0.f);
  float o1 = fmaxf(fmaf(d, a[1], b1.y), 0.f);
  float o2 = fmaxf(fmaf(d, a[2], b1.z), 0.f);
  float o3 = fmaxf(fmaf(d, a[3], b1.w), 0.f);
  float o4 = fmaxf(fmaf(d, a[4], b2.x), 0.f);
  float o5 = fmaxf(fmaf(d, a[5], b2.y), 0.f);
  float o6 = fmaxf(fmaf(d, a[6], b2.z), 0.f);
  float o7 = fmaxf(fmaf(d, a[7], b2.w), 0.f);
  uint4 ov;
  ov.x = pack2bf(o0, o1);
  ov.y = pack2bf(o2, o3);
  ov.z = pack2bf(o4, o5);
  ov.w = pack2bf(o6, o7);
  *(uint4*)(out16 + (size_t)node * (FD / 2) + lane * 4) = ov;
}

// ---------- pooling (bf16 h; 64 threads/block, thread f = features 2f,2f+1) ----------

__global__ void k_pool(const uint* __restrict__ h16, const int* __restrict__ batch,
                       float* __restrict__ addp, float* __restrict__ cnt,
                       unsigned int* __restrict__ maxp) {
  const int PN = 64;
  int f = threadIdx.x;  // 0..63
  int n0 = blockIdx.x * PN;
  if (n0 >= NN) return;
  int n1 = n0 + PN; if (n1 > NN) n1 = NN;
  int curg = batch[n0];
  float s0 = 0.f, s1 = 0.f, m0 = 0.f, m1 = 0.f;
  int c = 0;
  for (int n = n0; n < n1; ++n) {
    int gi = batch[n];
    if (gi != curg) {
      atomicAdd(&addp[curg * FD + 2 * f], s0);
      atomicAdd(&addp[curg * FD + 2 * f + 1], s1);
      atomicMax(&maxp[curg * FD + 2 * f], __float_as_uint(m0));
      atomicMax(&maxp[curg * FD + 2 * f + 1], __float_as_uint(m1));
      if (f == 0) atomicAdd(&cnt[curg], (float)c);
      s0 = 0.f; s1 = 0.f; m0 = 0.f; m1 = 0.f; c = 0; curg = gi;
    }
    uint u = h16[(size_t)n * (FD / 2) + f];
    float lo = BFLO(u), hi = BFHI(u);
    s0 += lo; s1 += hi;
    m0 = fmaxf(m0, lo); m1 = fmaxf(m1, hi);
    c += 1;
  }
  atomicAdd(&addp[curg * FD + 2 * f], s0);
  atomicAdd(&addp[curg * FD + 2 * f + 1], s1);
  atomicMax(&maxp[curg * FD + 2 * f], __float_as_uint(m0));   // h >= 0 post-relu
  atomicMax(&maxp[curg * FD + 2 * f + 1], __float_as_uint(m1));
  if (f == 0) atomicAdd(&cnt[curg], (float)c);
}

// ---------- enc assembly + 2-layer MLP ----------

__global__ void k_final(const float* __restrict__ addp, const float* __restrict__ cnt,
                        const unsigned int* __restrict__ maxp,
                        const float* __restrict__ l1w, const float* __restrict__ l1b,
                        const float* __restrict__ l2w, const float* __restrict__ l2b,
                        float* __restrict__ d_out) {
  __shared__ float enc_s[384];
  __shared__ float hid_s[128];
  int gph = blockIdx.x, j = threadIdx.x;
  float a = addp[gph * FD + j];
  float c = cnt[gph];
  float mn = a / fmaxf(c, 1.f);
  float mx = __uint_as_float(maxp[gph * FD + j]);
  enc_s[j] = a; enc_s[128 + j] = mn; enc_s[256 + j] = mx;
  float* enc_out = d_out + 2 * NG;
  enc_out[gph * 384 + j] = a;
  enc_out[gph * 384 + 128 + j] = mn;
  enc_out[gph * 384 + 256 + j] = mx;
  __syncthreads();
  float sacc = l1b[j];
  for (int k = 0; k < 384; ++k) sacc = fmaf(enc_s[k], l1w[k * FD + j], sacc);
  hid_s[j] = fmaxf(sacc, 0.f);
  __syncthreads();
  if (j < 2) {
    float o = l2b[j];
    for (int k = 0; k < FD; ++k) o = fmaf(hid_s[k], l2w[k * 2 + j], o);
    d_out[gph * 2 + j] = o;
  }
}

extern "C" void kernel_launch(void* const* d_in, const int* in_sizes, int n_in,
                              void* d_out, int out_size, void* d_ws, size_t ws_size,
                              hipStream_t stream) {
  const float* x      = (const float*)d_in[0];
  const int*   edge   = (const int*)d_in[1];
  const int*   batch  = (const int*)d_in[2];
  const float* conv_w = (const float*)d_in[3];
  const float* conv_b = (const float*)d_in[4];
  const float* l1w    = (const float*)d_in[5];
  const float* l1b    = (const float*)d_in[6];
  const float* l2w    = (const float*)d_in[7];
  const float* l2b    = (const float*)d_in[8];
  float* out = (float*)d_out;

  const int* esrc = edge;
  const int* edst = edge + NE;

  char* wsp = (char*)d_ws;
  auto alloc = [&](size_t bytes) -> char* {
    char* p = wsp;
    wsp += (bytes + 255) & ~(size_t)255;
    return p;
  };
  uint*  gbuf    = (uint*)alloc(2u * NN * FD);   // bf16 g, 12.8 MB
  uint*  hbuf    = (uint*)alloc(2u * NN * FD);   // bf16 h, 12.8 MB
  int*   csr_src = (int*)alloc(sizeof(int) * NE);
  int*   indeg   = (int*)alloc(sizeof(int) * NN);
  int*   row_off = (int*)alloc(sizeof(int) * (NN + 1));
  int*   cursor  = (int*)alloc(sizeof(int) * NN);
  int*   locpre  = (int*)alloc(sizeof(int) * NN);
  int*   blocksum= (int*)alloc(sizeof(int) * SCAN_NB);
  int*   blockoff= (int*)alloc(sizeof(int) * SCAN_NB);
  float* dinv    = (float*)alloc(sizeof(float) * NN);
  float* addp    = (float*)alloc(sizeof(float) * NG * FD);
  float* cnt     = (float*)alloc(sizeof(float) * NG);
  unsigned int* maxp = (unsigned int*)alloc(sizeof(unsigned int) * NG * FD);

  k_zero<<<(NN + 255) / 256, 256, 0, stream>>>(indeg, addp, cnt, maxp);

  k_count<<<NROLE * NCHUNK, 256, 0, stream>>>(edst, indeg);
  k_scan1<<<SCAN_NB, 256, 0, stream>>>(indeg, locpre, blocksum);
  k_scan2<<<1, 256, 0, stream>>>(blocksum, blockoff, row_off);
  k_scan3<<<SCAN_NB, 256, 0, stream>>>(indeg, locpre, blockoff, row_off, dinv, cursor);
  k_fill<<<NROLE * NCHUNK, 256, 0, stream>>>(esrc, edst, cursor, csr_src);

  // layer 0 (fp32 x input)
  k_matmul_f32<<<(NN + 63) / 64, 256, 0, stream>>>(x, conv_w + 0 * FD * FD, dinv, gbuf);
  k_agg<<<(NN + 15) / 16, 256, 0, stream>>>(gbuf, row_off, csr_src, dinv, conv_b + 0 * FD, hbuf);
  // layers 1..2 (bf16 h input)
  for (int l = 1; l < 3; ++l) {
    k_matmul_b16<<<(NN + 63) / 64, 256, 0, stream>>>(hbuf, conv_w + l * FD * FD, dinv, gbuf);
    k_agg<<<(NN + 15) / 16, 256, 0, stream>>>(gbuf, row_off, csr_src, dinv, conv_b + l * FD, hbuf);
  }

  k_pool<<<(NN + 63) / 64, 64, 0, stream>>>(hbuf, batch, addp, cnt, maxp);
  k_final<<<NG, 128, 0, stream>>>(addp, cnt, maxp, l1w, l1b, l2w, l2b, out);
}

// Round 9
// 263.212 us; speedup vs baseline: 14.2154x; 1.2010x over previous
//
#include <hip/hip_runtime.h>

#define NN 50000
#define NE 800000
#define NG 64
#define FD 128
#define SCAN_NB ((NN + 255) / 256)   // 196 scan blocks
#define NROLE 8                      // XCD count heuristic (blockIdx % 8)
#define NCHUNK 98                    // edge chunks per role
#define NODES_PER_ROLE (NN / NROLE)  // 6250 exactly

typedef unsigned int uint;
typedef unsigned short ushort;
typedef __attribute__((ext_vector_type(8))) short short8v;  // 8 bf16 (4 VGPR)
typedef __attribute__((ext_vector_type(4))) float f32x4;    // MFMA acc

// RNE fp32 -> bf16 pair packed into one uint (lo ushort = first elem)
__device__ __forceinline__ uint pack2bf(float a, float b) {
  uint ua = __float_as_uint(a);
  uint ub = __float_as_uint(b);
  ua = (ua + 0x7fffu + ((ua >> 16) & 1u)) >> 16;
  ub = (ub + 0x7fffu + ((ub >> 16) & 1u)) >> 16;
  return ua | (ub << 16);
}

__device__ __forceinline__ ushort bf16of(float v) {
  uint u = __float_as_uint(v);
  u = (u + 0x7fffu + ((u >> 16) & 1u)) >> 16;
  return (ushort)u;
}

#define BFLO(u) __uint_as_float((u) << 16)
#define BFHI(u) __uint_as_float((u) & 0xffff0000u)

// ---------- workspace zeroing ----------

__global__ void k_zero(int* __restrict__ indeg, float* __restrict__ addp,
                       float* __restrict__ cnt, uint* __restrict__ maxp) {
  int i = blockIdx.x * 256 + threadIdx.x;
  if (i < NN) indeg[i] = 0;
  if (i < NG * FD) { addp[i] = 0.f; maxp[i] = 0u; }
  if (i < NG) cnt[i] = 0.f;
}

// ---------- W fragment pre-pack (fp32 W -> bf16 MFMA B-fragments) ----------
// For layer L, ktile t (k0=32t), ntile nt (n0=16nt): lane l holds
// B[k][n0 + (l&15)] for k = k0 + 8*(l>>4) + j, j=0..7, packed as uint4.

__global__ void k_wprep(const float* __restrict__ conv_w, uint* __restrict__ w16) {
  int id = blockIdx.x;                 // layer*32 + t*8 + nt  (96 blocks)
  int layer = id >> 5;
  int t = (id >> 3) & 3;
  int nt = id & 7;
  int l = threadIdx.x;                 // 64 lanes
  const float* W = conv_w + layer * FD * FD;
  int col = nt * 16 + (l & 15);
  int k0 = t * 32 + 8 * (l >> 4);
  uint4 u;
  u.x = pack2bf(W[(k0 + 0) * FD + col], W[(k0 + 1) * FD + col]);
  u.y = pack2bf(W[(k0 + 2) * FD + col], W[(k0 + 3) * FD + col]);
  u.z = pack2bf(W[(k0 + 4) * FD + col], W[(k0 + 5) * FD + col]);
  u.w = pack2bf(W[(k0 + 6) * FD + col], W[(k0 + 7) * FD + col]);
  ((uint4*)w16)[id * 64 + l] = u;
}

// ---------- CSR build (XCD-sharded; see R7 notes) ----------

__global__ void k_count(const int* __restrict__ dst, int* __restrict__ indeg) {
  int role = blockIdx.x & (NROLE - 1);
  int chunk = blockIdx.x >> 3;
  int lo = role * NODES_PER_ROLE, hi = lo + NODES_PER_ROLE;
  for (int i = chunk * 256 + threadIdx.x; i < NE / 4; i += NCHUNK * 256) {
    int4 d = ((const int4*)dst)[i];
    if (d.x >= lo && d.x < hi) atomicAdd(&indeg[d.x], 1);
    if (d.y >= lo && d.y < hi) atomicAdd(&indeg[d.y], 1);
    if (d.z >= lo && d.z < hi) atomicAdd(&indeg[d.z], 1);
    if (d.w >= lo && d.w < hi) atomicAdd(&indeg[d.w], 1);
  }
}

__global__ void k_scan1(const int* __restrict__ indeg, int* __restrict__ locpre,
                        int* __restrict__ blocksum) {
  __shared__ int sums[256];
  int t = threadIdx.x;
  int idx = blockIdx.x * 256 + t;
  int v = (idx < NN) ? indeg[idx] : 0;
  sums[t] = v;
  __syncthreads();
  for (int off = 1; off < 256; off <<= 1) {
    int u = (t >= off) ? sums[t - off] : 0;
    __syncthreads();
    sums[t] += u;
    __syncthreads();
  }
  if (idx < NN) locpre[idx] = sums[t] - v;
  if (t == 255) blocksum[blockIdx.x] = sums[255];
}

__global__ void k_scan2(int* __restrict__ blocksum, int* __restrict__ blockoff,
                        int* __restrict__ row_off) {
  __shared__ int sums[256];
  int t = threadIdx.x;
  int v = (t < SCAN_NB) ? blocksum[t] : 0;
  sums[t] = v;
  __syncthreads();
  for (int off = 1; off < 256; off <<= 1) {
    int u = (t >= off) ? sums[t - off] : 0;
    __syncthreads();
    sums[t] += u;
    __syncthreads();
  }
  if (t < SCAN_NB) blockoff[t] = sums[t] - v;
  if (t == 255) row_off[NN] = sums[255];
}

__global__ void k_scan3(const int* __restrict__ indeg, const int* __restrict__ locpre,
                        const int* __restrict__ blockoff, int* __restrict__ row_off,
                        float* __restrict__ dinv, int* __restrict__ cursor) {
  int idx = blockIdx.x * 256 + threadIdx.x;
  if (idx < NN) {
    int ro = blockoff[blockIdx.x] + locpre[idx];
    row_off[idx] = ro;
    cursor[idx] = ro;
    dinv[idx] = rsqrtf((float)(indeg[idx] + 1));  // +1 self-loop
  }
}

__global__ void k_fill(const int* __restrict__ src, const int* __restrict__ dst,
                       int* __restrict__ cursor, int* __restrict__ csr_src) {
  int role = blockIdx.x & (NROLE - 1);
  int chunk = blockIdx.x >> 3;
  int lo = role * NODES_PER_ROLE, hi = lo + NODES_PER_ROLE;
  for (int i = chunk * 256 + threadIdx.x; i < NE / 4; i += NCHUNK * 256) {
    int4 s = ((const int4*)src)[i];
    int4 d = ((const int4*)dst)[i];
    if (d.x >= lo && d.x < hi) { int p = atomicAdd(&cursor[d.x], 1); csr_src[p] = s.x; }
    if (d.y >= lo && d.y < hi) { int p = atomicAdd(&cursor[d.y], 1); csr_src[p] = s.y; }
    if (d.z >= lo && d.z < hi) { int p = atomicAdd(&cursor[d.z], 1); csr_src[p] = s.z; }
    if (d.w >= lo && d.w < hi) { int p = atomicAdd(&cursor[d.w], 1); csr_src[p] = s.w; }
  }
}

// ---------- dense via MFMA: g[i][:] = bf16(dinv[i] * (h[i][:] @ W)) ----------
// 64 rows x 128 cols per 256-thread block (4 waves x 16 rows). Per wave:
// 4 K-steps x 8 ntiles of mfma_f32_16x16x32_bf16.
// A: lane l -> row=l&15, k=8*(l>>4)+j (contiguous 8 = one uint4 of the row).
// B: pre-packed fragments from k_wprep. D: col=l&15, row=4*(l>>4)+reg [m89].

__global__ __launch_bounds__(256) void k_mm_b16(const uint* __restrict__ h16,
                                                const uint* __restrict__ wfrag,
                                                const float* __restrict__ dinv,
                                                uint* __restrict__ g16) {
  int tid = threadIdx.x;
  int wv = tid >> 6, l = tid & 63;
  int lr = l & 15, lg = l >> 4;
  int row0 = blockIdx.x * 64 + wv * 16;
  const uint4* wl = (const uint4*)wfrag;
  int arow = row0 + lr; if (arow > NN - 1) arow = NN - 1;
  const uint* hrow = h16 + (size_t)arow * (FD / 2);
  f32x4 acc[8] = {};
#pragma unroll 2
  for (int t = 0; t < 4; ++t) {
    uint4 a = *(const uint4*)(hrow + t * 16 + 4 * lg);
    short8v av = __builtin_bit_cast(short8v, a);
#pragma unroll
    for (int nt = 0; nt < 8; ++nt) {
      uint4 b = wl[(t * 8 + nt) * 64 + l];
      short8v bv = __builtin_bit_cast(short8v, b);
      acc[nt] = __builtin_amdgcn_mfma_f32_16x16x32_bf16(av, bv, acc[nt], 0, 0, 0);
    }
  }
  ushort* gout = (ushort*)g16;
#pragma unroll
  for (int r = 0; r < 4; ++r) {
    int row = row0 + 4 * lg + r;
    bool ok = row < NN;
    float d = dinv[ok ? row : 0];
#pragma unroll
    for (int nt = 0; nt < 8; ++nt) {
      if (ok) gout[(size_t)row * FD + nt * 16 + lr] = bf16of(acc[nt][r] * d);
    }
  }
}

// layer 0: fp32 x input, cast to bf16 fragments on the fly
__global__ __launch_bounds__(256) void k_mm_f32(const float* __restrict__ x,
                                                const uint* __restrict__ wfrag,
                                                const float* __restrict__ dinv,
                                                uint* __restrict__ g16) {
  int tid = threadIdx.x;
  int wv = tid >> 6, l = tid & 63;
  int lr = l & 15, lg = l >> 4;
  int row0 = blockIdx.x * 64 + wv * 16;
  const uint4* wl = (const uint4*)wfrag;
  int arow = row0 + lr; if (arow > NN - 1) arow = NN - 1;
  const float* xrow = x + (size_t)arow * FD;
  f32x4 acc[8] = {};
#pragma unroll 2
  for (int t = 0; t < 4; ++t) {
    float4 p = *(const float4*)(xrow + t * 32 + 8 * lg);
    float4 q = *(const float4*)(xrow + t * 32 + 8 * lg + 4);
    uint4 a;
    a.x = pack2bf(p.x, p.y); a.y = pack2bf(p.z, p.w);
    a.z = pack2bf(q.x, q.y); a.w = pack2bf(q.z, q.w);
    short8v av = __builtin_bit_cast(short8v, a);
#pragma unroll
    for (int nt = 0; nt < 8; ++nt) {
      uint4 b = wl[(t * 8 + nt) * 64 + l];
      short8v bv = __builtin_bit_cast(short8v, b);
      acc[nt] = __builtin_amdgcn_mfma_f32_16x16x32_bf16(av, bv, acc[nt], 0, 0, 0);
    }
  }
  ushort* gout = (ushort*)g16;
#pragma unroll
  for (int r = 0; r < 4; ++r) {
    int row = row0 + 4 * lg + r;
    bool ok = row < NN;
    float d = dinv[ok ? row : 0];
#pragma unroll
    for (int nt = 0; nt < 8; ++nt) {
      if (ok) gout[(size_t)row * FD + nt * 16 + lr] = bf16of(acc[nt][r] * d);
    }
  }
}

// ---------- sparse: h' = bf16(relu(dinv*(sum g[s] + g[node]) + b)) ----------

__global__ __launch_bounds__(256) void k_agg(const uint* __restrict__ g16,
                                             const int* __restrict__ row_off,
                                             const int* __restrict__ csr_src,
                                             const float* __restrict__ dinv,
                                             const float* __restrict__ bias,
                                             uint* __restrict__ out16) {
  int node = blockIdx.x * 16 + (threadIdx.x >> 4);
  int lane = threadIdx.x & 15;
  if (node >= NN) return;
  const uint4* gp = (const uint4*)g16;  // 16 uint4 per row
  float a[8];
  uint4 sv = gp[(size_t)node * 16 + lane];
  a[0] = BFLO(sv.x); a[1] = BFHI(sv.x);
  a[2] = BFLO(sv.y); a[3] = BFHI(sv.y);
  a[4] = BFLO(sv.z); a[5] = BFHI(sv.z);
  a[6] = BFLO(sv.w); a[7] = BFHI(sv.w);

#define ACC8(v)                                      \
  a[0] += BFLO(v.x); a[1] += BFHI(v.x);              \
  a[2] += BFLO(v.y); a[3] += BFHI(v.y);              \
  a[4] += BFLO(v.z); a[5] += BFHI(v.z);              \
  a[6] += BFLO(v.w); a[7] += BFHI(v.w);

  int e0 = row_off[node], e1 = row_off[node + 1];
  int e = e0;
  for (; e + 4 <= e1; e += 4) {
    int s0 = csr_src[e + 0];
    int s1 = csr_src[e + 1];
    int s2 = csr_src[e + 2];
    int s3 = csr_src[e + 3];
    uint4 v0 = gp[(size_t)s0 * 16 + lane];
    uint4 v1 = gp[(size_t)s1 * 16 + lane];
    uint4 v2 = gp[(size_t)s2 * 16 + lane];
    uint4 v3 = gp[(size_t)s3 * 16 + lane];
    ACC8(v0) ACC8(v1) ACC8(v2) ACC8(v3)
  }
  for (; e < e1; ++e) {
    int s = csr_src[e];
    uint4 v = gp[(size_t)s * 16 + lane];
    ACC8(v)
  }
#undef ACC8

  float d = dinv[node];
  int f0 = lane * 8;
  float4 b1 = *(const float4*)(bias + f0);
  float4 b2 = *(const float4*)(bias + f0 + 4);
  float o0 = fmaxf(fmaf(d, a[0], b1.x), 0.f);
  float o1 = fmaxf(fmaf(d, a[1], b1.y), 0.f);
  float o2 = fmaxf(fmaf(d, a[2], b1.z), 0.f);
  float o3 = fmaxf(fmaf(d, a[3], b1.w), 0.f);
  float o4 = fmaxf(fmaf(d, a[4], b2.x), 0.f);
  float o5 = fmaxf(fmaf(d, a[5], b2.y), 0.f);
  float o6 = fmaxf(fmaf(d, a[6], b2.z), 0.f);
  float o7 = fmaxf(fmaf(d, a[7], b2.w), 0.f);
  uint4 ov;
  ov.x = pack2bf(o0, o1);
  ov.y = pack2bf(o2, o3);
  ov.z = pack2bf(o4, o5);
  ov.w = pack2bf(o6, o7);
  *(uint4*)(out16 + (size_t)node * (FD / 2) + lane * 4) = ov;
}

// ---------- pooling (bf16 h; 64 threads/block, thread f = features 2f,2f+1) ----------

__global__ void k_pool(const uint* __restrict__ h16, const int* __restrict__ batch,
                       float* __restrict__ addp, float* __restrict__ cnt,
                       unsigned int* __restrict__ maxp) {
  const int PN = 64;
  int f = threadIdx.x;  // 0..63
  int n0 = blockIdx.x * PN;
  if (n0 >= NN) return;
  int n1 = n0 + PN; if (n1 > NN) n1 = NN;
  int curg = batch[n0];
  float s0 = 0.f, s1 = 0.f, m0 = 0.f, m1 = 0.f;
  int c = 0;
  for (int n = n0; n < n1; ++n) {
    int gi = batch[n];
    if (gi != curg) {
      atomicAdd(&addp[curg * FD + 2 * f], s0);
      atomicAdd(&addp[curg * FD + 2 * f + 1], s1);
      atomicMax(&maxp[curg * FD + 2 * f], __float_as_uint(m0));
      atomicMax(&maxp[curg * FD + 2 * f + 1], __float_as_uint(m1));
      if (f == 0) atomicAdd(&cnt[curg], (float)c);
      s0 = 0.f; s1 = 0.f; m0 = 0.f; m1 = 0.f; c = 0; curg = gi;
    }
    uint u = h16[(size_t)n * (FD / 2) + f];
    float lo = BFLO(u), hi = BFHI(u);
    s0 += lo; s1 += hi;
    m0 = fmaxf(m0, lo); m1 = fmaxf(m1, hi);
    c += 1;
  }
  atomicAdd(&addp[curg * FD + 2 * f], s0);
  atomicAdd(&addp[curg * FD + 2 * f + 1], s1);
  atomicMax(&maxp[curg * FD + 2 * f], __float_as_uint(m0));   // h >= 0 post-relu
  atomicMax(&maxp[curg * FD + 2 * f + 1], __float_as_uint(m1));
  if (f == 0) atomicAdd(&cnt[curg], (float)c);
}

// ---------- enc assembly + 2-layer MLP ----------

__global__ void k_final(const float* __restrict__ addp, const float* __restrict__ cnt,
                        const unsigned int* __restrict__ maxp,
                        const float* __restrict__ l1w, const float* __restrict__ l1b,
                        const float* __restrict__ l2w, const float* __restrict__ l2b,
                        float* __restrict__ d_out) {
  __shared__ float enc_s[384];
  __shared__ float hid_s[128];
  int gph = blockIdx.x, j = threadIdx.x;
  float a = addp[gph * FD + j];
  float c = cnt[gph];
  float mn = a / fmaxf(c, 1.f);
  float mx = __uint_as_float(maxp[gph * FD + j]);
  enc_s[j] = a; enc_s[128 + j] = mn; enc_s[256 + j] = mx;
  float* enc_out = d_out + 2 * NG;
  enc_out[gph * 384 + j] = a;
  enc_out[gph * 384 + 128 + j] = mn;
  enc_out[gph * 384 + 256 + j] = mx;
  __syncthreads();
  float sacc = l1b[j];
  for (int k = 0; k < 384; ++k) sacc = fmaf(enc_s[k], l1w[k * FD + j], sacc);
  hid_s[j] = fmaxf(sacc, 0.f);
  __syncthreads();
  if (j < 2) {
    float o = l2b[j];
    for (int k = 0; k < FD; ++k) o = fmaf(hid_s[k], l2w[k * 2 + j], o);
    d_out[gph * 2 + j] = o;
  }
}

extern "C" void kernel_launch(void* const* d_in, const int* in_sizes, int n_in,
                              void* d_out, int out_size, void* d_ws, size_t ws_size,
                              hipStream_t stream) {
  const float* x      = (const float*)d_in[0];
  const int*   edge   = (const int*)d_in[1];
  const int*   batch  = (const int*)d_in[2];
  const float* conv_w = (const float*)d_in[3];
  const float* conv_b = (const float*)d_in[4];
  const float* l1w    = (const float*)d_in[5];
  const float* l1b    = (const float*)d_in[6];
  const float* l2w    = (const float*)d_in[7];
  const float* l2b    = (const float*)d_in[8];
  float* out = (float*)d_out;

  const int* esrc = edge;
  const int* edst = edge + NE;

  char* wsp = (char*)d_ws;
  auto alloc = [&](size_t bytes) -> char* {
    char* p = wsp;
    wsp += (bytes + 255) & ~(size_t)255;
    return p;
  };
  uint*  gbuf    = (uint*)alloc(2u * NN * FD);        // bf16 g, 12.8 MB
  uint*  hbuf    = (uint*)alloc(2u * NN * FD);        // bf16 h, 12.8 MB
  uint*  w16     = (uint*)alloc(2u * 3 * FD * FD);    // bf16 W frags, 96 KB
  int*   csr_src = (int*)alloc(sizeof(int) * NE);
  int*   indeg   = (int*)alloc(sizeof(int) * NN);
  int*   row_off = (int*)alloc(sizeof(int) * (NN + 1));
  int*   cursor  = (int*)alloc(sizeof(int) * NN);
  int*   locpre  = (int*)alloc(sizeof(int) * NN);
  int*   blocksum= (int*)alloc(sizeof(int) * SCAN_NB);
  int*   blockoff= (int*)alloc(sizeof(int) * SCAN_NB);
  float* dinv    = (float*)alloc(sizeof(float) * NN);
  float* addp    = (float*)alloc(sizeof(float) * NG * FD);
  float* cnt     = (float*)alloc(sizeof(float) * NG);
  unsigned int* maxp = (unsigned int*)alloc(sizeof(unsigned int) * NG * FD);

  k_zero<<<(NN + 255) / 256, 256, 0, stream>>>(indeg, addp, cnt, maxp);
  k_wprep<<<96, 64, 0, stream>>>(conv_w, w16);

  k_count<<<NROLE * NCHUNK, 256, 0, stream>>>(edst, indeg);
  k_scan1<<<SCAN_NB, 256, 0, stream>>>(indeg, locpre, blocksum);
  k_scan2<<<1, 256, 0, stream>>>(blocksum, blockoff, row_off);
  k_scan3<<<SCAN_NB, 256, 0, stream>>>(indeg, locpre, blockoff, row_off, dinv, cursor);
  k_fill<<<NROLE * NCHUNK, 256, 0, stream>>>(esrc, edst, cursor, csr_src);

  const int MM_GRID = (NN + 63) / 64;   // 782
  // layer 0 (fp32 x input)
  k_mm_f32<<<MM_GRID, 256, 0, stream>>>(x, w16, dinv, gbuf);
  k_agg<<<(NN + 15) / 16, 256, 0, stream>>>(gbuf, row_off, csr_src, dinv, conv_b + 0 * FD, hbuf);
  // layers 1..2 (bf16 h input); per-layer W-frag block = FD*FD/2 uints (32 KB)
  for (int l = 1; l < 3; ++l) {
    k_mm_b16<<<MM_GRID, 256, 0, stream>>>(hbuf, w16 + l * (FD * FD / 2), dinv, gbuf);
    k_agg<<<(NN + 15) / 16, 256, 0, stream>>>(gbuf, row_off, csr_src, dinv, conv_b + l * FD, hbuf);
  }

  k_pool<<<(NN + 63) / 64, 64, 0, stream>>>(hbuf, batch, addp, cnt, maxp);
  k_final<<<NG, 128, 0, stream>>>(addp, cnt, maxp, l1w, l1b, l2w, l2b, out);
}